// Round 5
// baseline (791.196 us; speedup 1.0000x reference)
//
#include <hip/hip_runtime.h>
#include <hip/hip_bf16.h>

#define Nn 100000
#define Ee 1600000
#define Kk 80000
#define NB ((Nn + 255) / 256)
#define BIGNEG -1e9f

typedef unsigned int uint;

struct Scal {
    uint prefix, remaining, needEq;
    float c1[4];
    float c2;
    uint gmaxOrd;
    float deng;
    float attnum[128];
    uint mxOrd[128];
};

__device__ __forceinline__ uint f2ord(float f) {
    uint b = __float_as_uint(f);
    return (b & 0x80000000u) ? ~b : (b | 0x80000000u);
}
__device__ __forceinline__ float ord2f(uint u) {
    uint b = (u & 0x80000000u) ? (u ^ 0x80000000u) : ~u;
    return __uint_as_float(b);
}
__device__ __forceinline__ float lrelu(float v) { return v > 0.f ? v : 0.2f * v; }

// ---------------- init ----------------
__global__ __launch_bounds__(256) void initK(uint* deg, uint* hist, Scal* sc) {
    int i = blockIdx.x * 256 + threadIdx.x;
    if (i < Nn) deg[i] = 0u;
    if (i < 256) hist[i] = 0u;
    if (i < 128) { sc->attnum[i] = 0.f; sc->mxOrd[i] = f2ord(0.0f); }
    if (i == 0) {
        sc->prefix = 0u; sc->remaining = Kk; sc->needEq = 0u;
        sc->deng = 0.f; sc->gmaxOrd = f2ord(-1e30f);
    }
}

__global__ void constK(const float* We1, const float* ae1, const float* We2, const float* ae2,
                       Scal* sc) {
    if (threadIdx.x == 0) {
        for (int h = 0; h < 4; h++) {
            float s = 0.f;
            for (int d = 0; d < 4; d++) s += We1[h * 4 + d] * ae1[h * 4 + d];
            sc->c1[h] = s;
        }
        float s2 = 0.f;
        for (int d = 0; d < 128; d++) s2 += We2[d] * ae2[d];
        sc->c2 = s2;
    }
}

// ---------------- layer 1: node GEMM + attn coefficients ----------------
__global__ __launch_bounds__(256) void nodeL1(const float* __restrict__ x,
                                              const float* __restrict__ W1,
                                              const float* __restrict__ as1,
                                              const float* __restrict__ ad1,
                                              float* __restrict__ hpre,
                                              float* __restrict__ alS1,
                                              float* __restrict__ alD1) {
    __shared__ float Ws[128 * 16];
    __shared__ float s_as[16], s_ad[16];
    for (int i = threadIdx.x; i < 2048; i += 256) Ws[i] = W1[i];
    if (threadIdx.x < 16) { s_as[threadIdx.x] = as1[threadIdx.x]; s_ad[threadIdx.x] = ad1[threadIdx.x]; }
    __syncthreads();
    int n = blockIdx.x * 256 + threadIdx.x;
    if (n >= Nn) return;
    float acc[16];
#pragma unroll
    for (int j = 0; j < 16; j++) acc[j] = 0.f;
    const float4* xr = (const float4*)(x + (size_t)n * 128);
    for (int t4 = 0; t4 < 32; t4++) {
        float4 xv = xr[t4];
#pragma unroll
        for (int j = 0; j < 16; j++) {
            acc[j] += xv.x * Ws[(t4 * 4 + 0) * 16 + j];
            acc[j] += xv.y * Ws[(t4 * 4 + 1) * 16 + j];
            acc[j] += xv.z * Ws[(t4 * 4 + 2) * 16 + j];
            acc[j] += xv.w * Ws[(t4 * 4 + 3) * 16 + j];
        }
    }
    float* hp = hpre + (size_t)n * 16;
#pragma unroll
    for (int j = 0; j < 16; j++) hp[j] = acc[j];
#pragma unroll
    for (int h = 0; h < 4; h++) {
        float s = 0.f, d = 0.f;
#pragma unroll
        for (int q = 0; q < 4; q++) {
            s += acc[h * 4 + q] * s_as[h * 4 + q];
            d += acc[h * 4 + q] * s_ad[h * 4 + q];
        }
        alS1[n * 4 + h] = s;
        alD1[n * 4 + h] = d;
    }
}

// ---------------- CSR build (dst-sorted) ----------------
__global__ __launch_bounds__(256) void degK(const int* __restrict__ ei, uint* __restrict__ deg) {
    int e = blockIdx.x * 256 + threadIdx.x;
    if (e >= Ee) return;
    atomicAdd(&deg[ei[Ee + e]], 1u);
}

__global__ __launch_bounds__(256) void scanA(const uint* __restrict__ deg, uint* __restrict__ rowstart,
                                             uint* __restrict__ blkSum) {
    __shared__ uint s[256];
    int i = blockIdx.x * 256 + threadIdx.x;
    uint v = (i < Nn) ? deg[i] : 0u;
    s[threadIdx.x] = v;
    __syncthreads();
    for (int off = 1; off < 256; off <<= 1) {
        uint t = (threadIdx.x >= off) ? s[threadIdx.x - off] : 0u;
        __syncthreads();
        s[threadIdx.x] += t;
        __syncthreads();
    }
    if (i < Nn) rowstart[i] = s[threadIdx.x] - v;  // exclusive within block
    if (threadIdx.x == 255) blkSum[blockIdx.x] = s[255];
}

__global__ __launch_bounds__(512) void scanB(const uint* __restrict__ blkSum, uint* __restrict__ blkOff) {
    __shared__ uint s[512];
    uint v = (threadIdx.x < NB) ? blkSum[threadIdx.x] : 0u;
    s[threadIdx.x] = v;
    __syncthreads();
    for (int off = 1; off < 512; off <<= 1) {
        uint t = (threadIdx.x >= off) ? s[threadIdx.x - off] : 0u;
        __syncthreads();
        s[threadIdx.x] += t;
        __syncthreads();
    }
    if (threadIdx.x < NB) blkOff[threadIdx.x] = s[threadIdx.x] - v;
}

__global__ __launch_bounds__(256) void scanC(uint* __restrict__ rowstart, const uint* __restrict__ blkOff,
                                             uint* __restrict__ cursor) {
    int i = blockIdx.x * 256 + threadIdx.x;
    if (i < Nn) {
        rowstart[i] += blkOff[blockIdx.x];
        cursor[i] = 0u;
    }
    if (i == 0) rowstart[Nn] = Ee;
}

__global__ __launch_bounds__(256) void fillK(const int* __restrict__ ei, const float* __restrict__ ea,
                                             const uint* __restrict__ rowstart, uint* __restrict__ cursor,
                                             int* __restrict__ csr_src, int* __restrict__ csr_dst,
                                             float* __restrict__ csr_ea) {
    int e = blockIdx.x * 256 + threadIdx.x;
    if (e >= Ee) return;
    int s = ei[e], d = ei[Ee + e];
    uint pos = atomicAdd(&cursor[d], 1u);
    uint idx = rowstart[d] + pos;
    csr_src[idx] = s;
    csr_dst[idx] = d;
    csr_ea[idx] = ea[e];
}

// ---------------- layer-1 gather: max pass + accumulate pass, thread per (dst,head) ----------------
__global__ __launch_bounds__(256) void gather1(const int* __restrict__ csr_src, const float* __restrict__ csr_ea,
                                               const uint* __restrict__ rowstart,
                                               const float* __restrict__ hpre, const float* __restrict__ alS1,
                                               const float* __restrict__ alD1, const Scal* __restrict__ sc,
                                               const float* __restrict__ b1, const float* __restrict__ Wrel,
                                               const float* __restrict__ Wroot,
                                               float* __restrict__ h1, float* __restrict__ p,
                                               float* __restrict__ q) {
    int tid = blockIdx.x * 256 + threadIdx.x;
    if (tid >= Nn * 4) return;
    int d = tid >> 2, h = tid & 3;
    uint r0 = rowstart[d], r1 = rowstart[d + 1];
    float ad = alD1[tid];
    float c1h = sc->c1[h];
    // pass 1: row max over scalars only
    float m = -1e30f;
#pragma unroll 4
    for (uint i = r0; i < r1; i++) {
        int s = csr_src[i];
        float v = lrelu(alS1[s * 4 + h] + ad + csr_ea[i] * c1h);
        m = fmaxf(m, v);
    }
    // pass 2: fixed-max accumulate, independent heavy loads
    float den = 0.f;
    float4 acc = {0.f, 0.f, 0.f, 0.f};
#pragma unroll 4
    for (uint i = r0; i < r1; i++) {
        int s = csr_src[i];
        float v = lrelu(alS1[s * 4 + h] + ad + csr_ea[i] * c1h);
        float e = __expf(v - m);
        float4 hv = *(const float4*)(hpre + (size_t)s * 16 + h * 4);
        den += e;
        acc.x += e * hv.x; acc.y += e * hv.y;
        acc.z += e * hv.z; acc.w += e * hv.w;
    }
    float inv = 1.f / fmaxf(den, 1e-16f);
    float4 o;
    o.x = fmaxf(acc.x * inv + b1[h * 4 + 0], 0.f);
    o.y = fmaxf(acc.y * inv + b1[h * 4 + 1], 0.f);
    o.z = fmaxf(acc.z * inv + b1[h * 4 + 2], 0.f);
    o.w = fmaxf(acc.w * inv + b1[h * 4 + 3], 0.f);
    *(float4*)(h1 + (size_t)d * 16 + h * 4) = o;
    // partial dots for GraphConv score: p = h1·Wrel, q = h1·Wroot, reduced over 4 head-lanes
    float pp = o.x * Wrel[h * 4 + 0] + o.y * Wrel[h * 4 + 1] + o.z * Wrel[h * 4 + 2] + o.w * Wrel[h * 4 + 3];
    float qq = o.x * Wroot[h * 4 + 0] + o.y * Wroot[h * 4 + 1] + o.z * Wroot[h * 4 + 2] + o.w * Wroot[h * 4 + 3];
    pp += __shfl_xor(pp, 1); pp += __shfl_xor(pp, 2);
    qq += __shfl_xor(qq, 1); qq += __shfl_xor(qq, 2);
    if (h == 0) { p[d] = pp; q[d] = qq; }
}

// ---------------- SAGPool score: score[d] = brel + q[d] + sum_row p[src] ----------------
__global__ __launch_bounds__(256) void scoreK2(const int* __restrict__ csr_src, const uint* __restrict__ rowstart,
                                               const float* __restrict__ p, const float* __restrict__ q,
                                               const float* __restrict__ brel,
                                               float* __restrict__ score, uint* __restrict__ dkey) {
    int d = blockIdx.x * 256 + threadIdx.x;
    if (d >= Nn) return;
    uint r0 = rowstart[d], r1 = rowstart[d + 1];
    float s = brel[0] + q[d];
#pragma unroll 4
    for (uint i = r0; i < r1; i++) s += p[csr_src[i]];
    score[d] = s;
    dkey[d] = ~f2ord(s);  // ascending dkey == descending score
}

// ---------------- radix select (k-th smallest dkey) ----------------
__global__ __launch_bounds__(256) void histK(const uint* __restrict__ dkey, const Scal* __restrict__ sc,
                                             uint* __restrict__ hist, int shift) {
    __shared__ uint lh[256];
    lh[threadIdx.x] = 0u;
    __syncthreads();
    int i = blockIdx.x * 256 + threadIdx.x;
    if (i < Nn) {
        uint d = dkey[i];
        bool ok = (shift == 24) || ((d >> (shift + 8)) == sc->prefix);
        if (ok) atomicAdd(&lh[(d >> shift) & 255u], 1u);
    }
    __syncthreads();
    if (lh[threadIdx.x]) atomicAdd(&hist[threadIdx.x], lh[threadIdx.x]);
}

__global__ void selK(Scal* sc, uint* hist) {
    if (threadIdx.x == 0) {
        uint rem = sc->remaining, cum = 0; int sel = 0;
        for (int b = 0; b < 256; b++) {
            uint c = hist[b];
            if (cum + c >= rem) { sel = b; break; }
            cum += c;
        }
        sc->remaining = rem - cum;
        sc->prefix = (sc->prefix << 8) | (uint)sel;
        for (int b = 0; b < 256; b++) hist[b] = 0u;
    }
}

__global__ __launch_bounds__(256) void cntK(const uint* __restrict__ dkey, const Scal* __restrict__ sc,
                                            uint* __restrict__ blkLt, uint* __restrict__ blkEq) {
    int i = blockIdx.x * 256 + threadIdx.x;
    uint ut = sc->prefix;
    bool lt = (i < Nn) && (dkey[i] < ut);
    bool eq = (i < Nn) && (dkey[i] == ut);
    __shared__ uint sl[4], se[4];
    unsigned long long bl = __ballot(lt), be = __ballot(eq);
    int lane = threadIdx.x & 63, w = threadIdx.x >> 6;
    if (lane == 0) { sl[w] = (uint)__popcll(bl); se[w] = (uint)__popcll(be); }
    __syncthreads();
    if (threadIdx.x == 0) {
        blkLt[blockIdx.x] = sl[0] + sl[1] + sl[2] + sl[3];
        blkEq[blockIdx.x] = se[0] + se[1] + se[2] + se[3];
    }
}

__global__ void prefK(Scal* sc, const uint* blkLt, const uint* blkEq, uint* eqPref) {
    if (threadIdx.x == 0) {
        uint tl = 0, te = 0;
        for (int b = 0; b < NB; b++) {
            eqPref[b] = te;
            tl += blkLt[b];
            te += blkEq[b];
        }
        sc->needEq = Kk - tl;
    }
}

__global__ __launch_bounds__(256) void keptK(const uint* __restrict__ dkey, const Scal* __restrict__ sc,
                                             const uint* __restrict__ eqPref, int* __restrict__ kept) {
    int i = blockIdx.x * 256 + threadIdx.x;
    uint ut = sc->prefix, needEq = sc->needEq;
    bool inr = i < Nn;
    uint d = inr ? dkey[i] : 0xFFFFFFFFu;
    bool isLt = inr && (d < ut);
    bool isEq = inr && (d == ut);
    __shared__ uint wcnt[4];
    unsigned long long mask = __ballot(isEq);
    int lane = threadIdx.x & 63, w = threadIdx.x >> 6;
    uint lanePre = (uint)__popcll(mask & ((1ull << lane) - 1ull));
    if (lane == 0) wcnt[w] = (uint)__popcll(mask);
    __syncthreads();
    uint wo = 0;
    for (int q = 0; q < 4; q++) if (q < w) wo += wcnt[q];
    uint rank = eqPref[blockIdx.x] + wo + lanePre;
    if (inr) kept[i] = (isLt || (isEq && rank < needEq)) ? 1 : 0;
}

// ---------------- layer 2 node transform: bf16 rows, lane owns dims (2l, 2l+1) ----------------
__global__ __launch_bounds__(256) void nodeL2(const float* __restrict__ h1, const float* __restrict__ score,
                                              const int* __restrict__ kept, const float* __restrict__ W2,
                                              const float* __restrict__ as2, const float* __restrict__ ad2,
                                              __hip_bfloat162* __restrict__ h2b, float* __restrict__ alS2,
                                              float* __restrict__ alD2) {
    __shared__ float Ws[16 * 128];
    for (int i = threadIdx.x; i < 2048; i += 256) Ws[i] = W2[i];
    __syncthreads();
    int wid = (blockIdx.x * 256 + threadIdx.x) >> 6;
    int lane = threadIdx.x & 63;
    if (wid >= Nn) return;
    int n = wid;
    if (!kept[n]) return;
    float t = tanhf(score[n]);
    float x2[16];
    const float* hr = h1 + (size_t)n * 16;
#pragma unroll
    for (int j = 0; j < 16; j++) x2[j] = hr[j] * t;
    int d0 = 2 * lane, d1 = 2 * lane + 1;
    float a0 = 0.f, a1 = 0.f;
    const float2* Wv = (const float2*)Ws;
#pragma unroll
    for (int j = 0; j < 16; j++) {
        float2 wv = Wv[j * 64 + lane];
        a0 += x2[j] * wv.x;
        a1 += x2[j] * wv.y;
    }
    __hip_bfloat162 hb;
    hb.x = __float2bfloat16(a0);
    hb.y = __float2bfloat16(a1);
    h2b[(size_t)n * 64 + lane] = hb;
    float s = a0 * as2[d0] + a1 * as2[d1];
    float dd = a0 * ad2[d0] + a1 * ad2[d1];
#pragma unroll
    for (int off = 32; off; off >>= 1) { s += __shfl_xor(s, off); dd += __shfl_xor(dd, off); }
    if (lane == 0) { alS2[n] = s; alD2[n] = dd; }
}

// ---------------- per-slot layer-2 logits (edge-parallel: full MLP on gathers) ----------------
__global__ __launch_bounds__(256) void edgeLg(const int* __restrict__ csr_src, const int* __restrict__ csr_dst,
                                              const float* __restrict__ csr_ea, const int* __restrict__ kept,
                                              const float* __restrict__ alS2, const float* __restrict__ alD2,
                                              const Scal* __restrict__ scc, float* __restrict__ csr_lg) {
    int i = blockIdx.x * 256 + threadIdx.x;
    if (i >= Ee) return;
    int s = csr_src[i];
    int d = csr_dst[i];
    float lg = -1e30f;
    if (kept[s] && kept[d])
        lg = lrelu(alS2[s] + alD2[d] + csr_ea[i] * scc->c2);
    csr_lg[i] = lg;
}

// ---------------- layer-2 gather: wave per kept dst, lane-parallel max + single accumulate ----------------
__global__ __launch_bounds__(256) void gather2(const int* __restrict__ csr_src,
                                               const float* __restrict__ csr_lg,
                                               const uint* __restrict__ rowstart, const int* __restrict__ kept,
                                               const __hip_bfloat162* __restrict__ h2b, const float* __restrict__ b2,
                                               const float* __restrict__ Wg, const float* __restrict__ bg,
                                               float* __restrict__ out2, float* __restrict__ gsc,
                                               Scal* sc) {
    __shared__ float wmax[4];
    int w = threadIdx.x >> 6, lane = threadIdx.x & 63;
    int n = blockIdx.x * 4 + w;
    float lmax = -1e30f;
    if (n < Nn && kept[n]) {
        uint r0 = rowstart[n], r1 = rowstart[n + 1];
        // lane-parallel row max (1 strided iter for deg<=64) + butterfly
        float m = -1e30f;
        for (uint i = r0 + lane; i < r1; i += 64) m = fmaxf(m, csr_lg[i]);
#pragma unroll
        for (int off = 32; off; off >>= 1) m = fmaxf(m, __shfl_xor(m, off));
        float den = 0.f, a0 = 0.f, a1 = 0.f;
        if (m > -1e29f) {
#pragma unroll 4
            for (uint i = r0; i < r1; i++) {
                float lg = csr_lg[i];
                if (lg > -1e29f) {  // wave-uniform: skip masked edges and their h2b load
                    float e = __expf(lg - m);
                    __hip_bfloat162 hb = h2b[(size_t)csr_src[i] * 64 + lane];
                    den += e;
                    a0 += e * __bfloat162float(hb.x);
                    a1 += e * __bfloat162float(hb.y);
                }
            }
        }
        float inv = 1.f / fmaxf(den, 1e-16f);
        float2 b2v = ((const float2*)b2)[lane];
        float2 wgv = ((const float2*)Wg)[lane];
        float o0 = fmaxf(a0 * inv + b2v.x, 0.f);
        float o1 = fmaxf(a1 * inv + b2v.y, 0.f);
        ((float2*)(out2 + (size_t)n * 128))[lane] = make_float2(o0, o1);
        float g = o0 * wgv.x + o1 * wgv.y;
#pragma unroll
        for (int off = 32; off; off >>= 1) g += __shfl_xor(g, off);
        g += bg[0];
        if (lane == 0) gsc[n] = g;
        lmax = g;
    }
    if (lane == 0) wmax[w] = lmax;
    __syncthreads();
    if (threadIdx.x == 0) {
        float mm = fmaxf(fmaxf(wmax[0], wmax[1]), fmaxf(wmax[2], wmax[3]));
        atomicMax(&sc->gmaxOrd, f2ord(mm));
    }
}

// gate-weighted sum + per-dim column max; out2 is already post-bias+relu
#define CHUNK 256
__global__ __launch_bounds__(128) void gateB(const float* __restrict__ out2, const float* __restrict__ gsc,
                                             const int* __restrict__ kept, Scal* sc) {
    int d = threadIdx.x;
    float gmax = ord2f(sc->gmaxOrd);
    float acc = 0.f, dacc = 0.f, mx = 0.f;
    int start = blockIdx.x * CHUNK;
    int end = start + CHUNK;
    if (end > Nn) end = Nn;
    for (int n = start; n < end; n++) {
        if (!kept[n]) continue;
        float h = out2[(size_t)n * 128 + d];
        float e = __expf(gsc[n] - gmax);
        acc += e * h;
        mx = fmaxf(mx, h);
        if (d == 0) dacc += e;
    }
    atomicAdd(&sc->attnum[d], acc);
    atomicMax(&sc->mxOrd[d], f2ord(mx));
    if (d == 0) atomicAdd(&sc->deng, dacc);
}

__global__ void outK(const Scal* sc, float* out) {
    int d = threadIdx.x;
    if (d < 128) {
        out[d] = sc->attnum[d] / sc->deng;
        out[128 + d] = ord2f(sc->mxOrd[d]);
    }
}

extern "C" void kernel_launch(void* const* d_in, const int* in_sizes, int n_in,
                              void* d_out, int out_size, void* d_ws, size_t ws_size,
                              hipStream_t stream) {
    const float* x = (const float*)d_in[0];
    const int* ei = (const int*)d_in[1];
    const float* ea = (const float*)d_in[2];
    const float* W1 = (const float*)d_in[3];
    const float* as1 = (const float*)d_in[4];
    const float* ad1 = (const float*)d_in[5];
    const float* We1 = (const float*)d_in[6];
    const float* ae1 = (const float*)d_in[7];
    const float* b1 = (const float*)d_in[8];
    const float* Wrel = (const float*)d_in[9];
    const float* brel = (const float*)d_in[10];
    const float* Wroot = (const float*)d_in[11];
    const float* W2 = (const float*)d_in[12];
    const float* as2 = (const float*)d_in[13];
    const float* ad2 = (const float*)d_in[14];
    const float* We2 = (const float*)d_in[15];
    const float* ae2 = (const float*)d_in[16];
    const float* b2 = (const float*)d_in[17];
    const float* Wg = (const float*)d_in[18];
    const float* bg = (const float*)d_in[19];
    float* out = (float*)d_out;

    float* base = (float*)d_ws;
    // Union region U (12.8M floats): out2 aliases all early-dead buffers.
    float* out2 = base;                               // [12.8M] written by gather2
    size_t o = 0;
    auto allocU = [&](size_t nf) { float* p2 = base + o; o += nf; return p2; };
    float* hpre = allocU((size_t)Nn * 16);            // dead after gather1
    float* h1 = allocU((size_t)Nn * 16);              // dead after nodeL2
    float* alS1 = allocU((size_t)Nn * 4);             // dead after gather1
    float* alD1 = allocU((size_t)Nn * 4);             // dead after gather1
    float* p = allocU(Nn);                            // dead after scoreK2
    float* q = allocU(Nn);                            // dead after scoreK2
    float* score = allocU(Nn);                        // dead after nodeL2
    uint* dkey = (uint*)allocU(Nn);                   // dead after keptK
    uint* deg = (uint*)allocU(Nn);                    // dead after scanA; reused as cursor
    uint* blkSum = (uint*)allocU(NB);
    uint* blkOff = (uint*)allocU(NB);
    uint* hist = (uint*)allocU(256);
    uint* blkLt = (uint*)allocU(NB);
    uint* blkEq = (uint*)allocU(NB);
    uint* eqPref = (uint*)allocU(NB);
    // persistent region after out2
    size_t oo = (size_t)Nn * 128;
    auto alloc = [&](size_t nf) { float* p2 = base + oo; oo += nf; return p2; };
    __hip_bfloat162* h2b = (__hip_bfloat162*)alloc((size_t)Nn * 64);  // bf16 [N][128]
    int* csr_src = (int*)alloc(Ee);
    int* csr_dst = (int*)alloc(Ee);
    float* csr_ea = alloc(Ee);
    float* csr_lg = alloc(Ee);
    uint* rowstart = (uint*)alloc(Nn + 1);
    int* kept = (int*)alloc(Nn);
    float* alS2 = alloc(Nn);
    float* alD2 = alloc(Nn);
    float* gsc = alloc(Nn);
    Scal* sc = (Scal*)alloc(512);
    uint* cursor = deg;  // alias: deg dead after scanA, cursor zeroed in scanC

    auto cdiv = [](long a, long b) { return (int)((a + b - 1) / b); };

    initK<<<NB, 256, 0, stream>>>(deg, hist, sc);
    constK<<<1, 64, 0, stream>>>(We1, ae1, We2, ae2, sc);
    nodeL1<<<NB, 256, 0, stream>>>(x, W1, as1, ad1, hpre, alS1, alD1);
    degK<<<cdiv(Ee, 256), 256, 0, stream>>>(ei, deg);
    scanA<<<NB, 256, 0, stream>>>(deg, rowstart, blkSum);
    scanB<<<1, 512, 0, stream>>>(blkSum, blkOff);
    scanC<<<NB, 256, 0, stream>>>(rowstart, blkOff, cursor);
    fillK<<<cdiv(Ee, 256), 256, 0, stream>>>(ei, ea, rowstart, cursor, csr_src, csr_dst, csr_ea);
    gather1<<<cdiv((long)Nn * 4, 256), 256, 0, stream>>>(csr_src, csr_ea, rowstart, hpre, alS1, alD1,
                                                         sc, b1, Wrel, Wroot, h1, p, q);
    scoreK2<<<NB, 256, 0, stream>>>(csr_src, rowstart, p, q, brel, score, dkey);
    for (int shift = 24; shift >= 0; shift -= 8) {
        histK<<<NB, 256, 0, stream>>>(dkey, sc, hist, shift);
        selK<<<1, 64, 0, stream>>>(sc, hist);
    }
    cntK<<<NB, 256, 0, stream>>>(dkey, sc, blkLt, blkEq);
    prefK<<<1, 64, 0, stream>>>(sc, blkLt, blkEq, eqPref);
    keptK<<<NB, 256, 0, stream>>>(dkey, sc, eqPref, kept);
    nodeL2<<<cdiv(Nn, 4), 256, 0, stream>>>(h1, score, kept, W2, as2, ad2, h2b, alS2, alD2);
    edgeLg<<<cdiv(Ee, 256), 256, 0, stream>>>(csr_src, csr_dst, csr_ea, kept, alS2, alD2, sc, csr_lg);
    gather2<<<cdiv(Nn, 4), 256, 0, stream>>>(csr_src, csr_lg, rowstart, kept,
                                             h2b, b2, Wg, bg, out2, gsc, sc);
    gateB<<<cdiv(Nn, CHUNK), 128, 0, stream>>>(out2, gsc, kept, sc);
    outK<<<1, 128, 0, stream>>>(sc, out);
}

// Round 6
// 784.480 us; speedup vs baseline: 1.0086x; 1.0086x over previous
//
#include <hip/hip_runtime.h>
#include <hip/hip_bf16.h>

#define Nn 100000
#define Ee 1600000
#define Kk 80000
#define NB ((Nn + 255) / 256)
#define BIGNEG -1e9f

typedef unsigned int uint;

struct Scal {
    uint prefix, remaining, needEq;
    float c1[4];
    float c2;
    uint gmaxOrd;
    float deng;
    float attnum[128];
    uint mxOrd[128];
};

__device__ __forceinline__ uint f2ord(float f) {
    uint b = __float_as_uint(f);
    return (b & 0x80000000u) ? ~b : (b | 0x80000000u);
}
__device__ __forceinline__ float ord2f(uint u) {
    uint b = (u & 0x80000000u) ? (u ^ 0x80000000u) : ~u;
    return __uint_as_float(b);
}
__device__ __forceinline__ float lrelu(float v) { return v > 0.f ? v : 0.2f * v; }

// ---------------- init ----------------
__global__ __launch_bounds__(256) void initK(uint* deg, uint* hist, Scal* sc) {
    int i = blockIdx.x * 256 + threadIdx.x;
    if (i < Nn) deg[i] = 0u;
    if (i < 256) hist[i] = 0u;
    if (i < 128) { sc->attnum[i] = 0.f; sc->mxOrd[i] = f2ord(0.0f); }
    if (i == 0) {
        sc->prefix = 0u; sc->remaining = Kk; sc->needEq = 0u;
        sc->deng = 0.f; sc->gmaxOrd = f2ord(-1e30f);
    }
}

__global__ void constK(const float* We1, const float* ae1, const float* We2, const float* ae2,
                       Scal* sc) {
    if (threadIdx.x == 0) {
        for (int h = 0; h < 4; h++) {
            float s = 0.f;
            for (int d = 0; d < 4; d++) s += We1[h * 4 + d] * ae1[h * 4 + d];
            sc->c1[h] = s;
        }
        float s2 = 0.f;
        for (int d = 0; d < 128; d++) s2 += We2[d] * ae2[d];
        sc->c2 = s2;
    }
}

// ---------------- layer 1: node GEMM + attn coefficients ----------------
__global__ __launch_bounds__(256) void nodeL1(const float* __restrict__ x,
                                              const float* __restrict__ W1,
                                              const float* __restrict__ as1,
                                              const float* __restrict__ ad1,
                                              float* __restrict__ hpre,
                                              float* __restrict__ alS1,
                                              float* __restrict__ alD1) {
    __shared__ float Ws[128 * 16];
    __shared__ float s_as[16], s_ad[16];
    for (int i = threadIdx.x; i < 2048; i += 256) Ws[i] = W1[i];
    if (threadIdx.x < 16) { s_as[threadIdx.x] = as1[threadIdx.x]; s_ad[threadIdx.x] = ad1[threadIdx.x]; }
    __syncthreads();
    int n = blockIdx.x * 256 + threadIdx.x;
    if (n >= Nn) return;
    float acc[16];
#pragma unroll
    for (int j = 0; j < 16; j++) acc[j] = 0.f;
    const float4* xr = (const float4*)(x + (size_t)n * 128);
    for (int t4 = 0; t4 < 32; t4++) {
        float4 xv = xr[t4];
#pragma unroll
        for (int j = 0; j < 16; j++) {
            acc[j] += xv.x * Ws[(t4 * 4 + 0) * 16 + j];
            acc[j] += xv.y * Ws[(t4 * 4 + 1) * 16 + j];
            acc[j] += xv.z * Ws[(t4 * 4 + 2) * 16 + j];
            acc[j] += xv.w * Ws[(t4 * 4 + 3) * 16 + j];
        }
    }
    float* hp = hpre + (size_t)n * 16;
#pragma unroll
    for (int j = 0; j < 16; j++) hp[j] = acc[j];
#pragma unroll
    for (int h = 0; h < 4; h++) {
        float s = 0.f, d = 0.f;
#pragma unroll
        for (int q = 0; q < 4; q++) {
            s += acc[h * 4 + q] * s_as[h * 4 + q];
            d += acc[h * 4 + q] * s_ad[h * 4 + q];
        }
        alS1[n * 4 + h] = s;
        alD1[n * 4 + h] = d;
    }
}

// ---------------- CSR build (dst-sorted) ----------------
__global__ __launch_bounds__(256) void degK(const int* __restrict__ ei, uint* __restrict__ deg) {
    int e = blockIdx.x * 256 + threadIdx.x;
    if (e >= Ee) return;
    atomicAdd(&deg[ei[Ee + e]], 1u);
}

__global__ __launch_bounds__(256) void scanA(const uint* __restrict__ deg, uint* __restrict__ rowstart,
                                             uint* __restrict__ blkSum) {
    __shared__ uint s[256];
    int i = blockIdx.x * 256 + threadIdx.x;
    uint v = (i < Nn) ? deg[i] : 0u;
    s[threadIdx.x] = v;
    __syncthreads();
    for (int off = 1; off < 256; off <<= 1) {
        uint t = (threadIdx.x >= off) ? s[threadIdx.x - off] : 0u;
        __syncthreads();
        s[threadIdx.x] += t;
        __syncthreads();
    }
    if (i < Nn) rowstart[i] = s[threadIdx.x] - v;  // exclusive within block
    if (threadIdx.x == 255) blkSum[blockIdx.x] = s[255];
}

__global__ __launch_bounds__(512) void scanB(const uint* __restrict__ blkSum, uint* __restrict__ blkOff) {
    __shared__ uint s[512];
    uint v = (threadIdx.x < NB) ? blkSum[threadIdx.x] : 0u;
    s[threadIdx.x] = v;
    __syncthreads();
    for (int off = 1; off < 512; off <<= 1) {
        uint t = (threadIdx.x >= off) ? s[threadIdx.x - off] : 0u;
        __syncthreads();
        s[threadIdx.x] += t;
        __syncthreads();
    }
    if (threadIdx.x < NB) blkOff[threadIdx.x] = s[threadIdx.x] - v;
}

__global__ __launch_bounds__(256) void scanC(uint* __restrict__ rowstart, const uint* __restrict__ blkOff,
                                             uint* __restrict__ cursor) {
    int i = blockIdx.x * 256 + threadIdx.x;
    if (i < Nn) {
        rowstart[i] += blkOff[blockIdx.x];
        cursor[i] = 0u;
    }
    if (i == 0) rowstart[Nn] = Ee;
}

__global__ __launch_bounds__(256) void fillK(const int* __restrict__ ei, const float* __restrict__ ea,
                                             const uint* __restrict__ rowstart, uint* __restrict__ cursor,
                                             int* __restrict__ csr_src, int* __restrict__ csr_dst,
                                             float* __restrict__ csr_ea) {
    int e = blockIdx.x * 256 + threadIdx.x;
    if (e >= Ee) return;
    int s = ei[e], d = ei[Ee + e];
    uint pos = atomicAdd(&cursor[d], 1u);
    uint idx = rowstart[d] + pos;
    csr_src[idx] = s;
    csr_dst[idx] = d;
    csr_ea[idx] = ea[e];
}

// ---------------- layer-1 per-slot logits (edge-parallel, 4 heads as float4) ----------------
__global__ __launch_bounds__(256) void edgeC1(const int* __restrict__ csr_src, const int* __restrict__ csr_dst,
                                              const float* __restrict__ csr_ea,
                                              const float* __restrict__ alS1, const float* __restrict__ alD1,
                                              const Scal* __restrict__ scc, float* __restrict__ csr_c1) {
    int i = blockIdx.x * 256 + threadIdx.x;
    if (i >= Ee) return;
    int s = csr_src[i], d = csr_dst[i];
    float4 as = *(const float4*)(alS1 + (size_t)s * 4);
    float4 av = *(const float4*)(alD1 + (size_t)d * 4);
    float eav = csr_ea[i];
    float4 o;
    o.x = lrelu(as.x + av.x + eav * scc->c1[0]);
    o.y = lrelu(as.y + av.y + eav * scc->c1[1]);
    o.z = lrelu(as.z + av.z + eav * scc->c1[2]);
    o.w = lrelu(as.w + av.w + eav * scc->c1[3]);
    *(float4*)(csr_c1 + (size_t)i * 4) = o;
}

// ---------------- layer-1 m/den per (dst,head): sequential reads only ----------------
__global__ __launch_bounds__(256) void mden1(const float* __restrict__ csr_c1, const uint* __restrict__ rowstart,
                                             float2* __restrict__ md1) {
    int tid = blockIdx.x * 256 + threadIdx.x;
    if (tid >= Nn * 4) return;
    int d = tid >> 2, h = tid & 3;
    uint r0 = rowstart[d], r1 = rowstart[d + 1];
    float m = -1e30f;
#pragma unroll 4
    for (uint i = r0; i < r1; i++) m = fmaxf(m, csr_c1[(size_t)i * 4 + h]);
    float den = 0.f;
#pragma unroll 4
    for (uint i = r0; i < r1; i++) den += __expf(csr_c1[(size_t)i * 4 + h] - m);
    md1[tid] = make_float2(m, 1.f / fmaxf(den, 1e-16f));
}

// ---------------- layer-1 gather: branch-free, pure fma, thread per (dst,head) ----------------
__global__ __launch_bounds__(256) void gather1b(const int* __restrict__ csr_src, const float* __restrict__ csr_c1,
                                                const uint* __restrict__ rowstart, const float2* __restrict__ md1,
                                                const float* __restrict__ hpre,
                                                const float* __restrict__ b1, const float* __restrict__ Wrel,
                                                const float* __restrict__ Wroot,
                                                float* __restrict__ h1, float* __restrict__ p,
                                                float* __restrict__ q) {
    int tid = blockIdx.x * 256 + threadIdx.x;
    if (tid >= Nn * 4) return;
    int d = tid >> 2, h = tid & 3;
    uint r0 = rowstart[d], r1 = rowstart[d + 1];
    float2 md = md1[tid];
    float4 acc = {0.f, 0.f, 0.f, 0.f};
#pragma unroll 8
    for (uint i = r0; i < r1; i++) {
        float e = __expf(csr_c1[(size_t)i * 4 + h] - md.x) * md.y;
        float4 hv = *(const float4*)(hpre + (size_t)csr_src[i] * 16 + h * 4);
        acc.x += e * hv.x; acc.y += e * hv.y;
        acc.z += e * hv.z; acc.w += e * hv.w;
    }
    float4 o;
    o.x = fmaxf(acc.x + b1[h * 4 + 0], 0.f);
    o.y = fmaxf(acc.y + b1[h * 4 + 1], 0.f);
    o.z = fmaxf(acc.z + b1[h * 4 + 2], 0.f);
    o.w = fmaxf(acc.w + b1[h * 4 + 3], 0.f);
    *(float4*)(h1 + (size_t)d * 16 + h * 4) = o;
    // partial dots for GraphConv score: p = h1·Wrel, q = h1·Wroot, reduced over 4 head-lanes
    float pp = o.x * Wrel[h * 4 + 0] + o.y * Wrel[h * 4 + 1] + o.z * Wrel[h * 4 + 2] + o.w * Wrel[h * 4 + 3];
    float qq = o.x * Wroot[h * 4 + 0] + o.y * Wroot[h * 4 + 1] + o.z * Wroot[h * 4 + 2] + o.w * Wroot[h * 4 + 3];
    pp += __shfl_xor(pp, 1); pp += __shfl_xor(pp, 2);
    qq += __shfl_xor(qq, 1); qq += __shfl_xor(qq, 2);
    if (h == 0) { p[d] = pp; q[d] = qq; }
}

// ---------------- SAGPool score: score[d] = brel + q[d] + sum_row p[src] ----------------
__global__ __launch_bounds__(256) void scoreK2(const int* __restrict__ csr_src, const uint* __restrict__ rowstart,
                                               const float* __restrict__ p, const float* __restrict__ q,
                                               const float* __restrict__ brel,
                                               float* __restrict__ score, uint* __restrict__ dkey) {
    int d = blockIdx.x * 256 + threadIdx.x;
    if (d >= Nn) return;
    uint r0 = rowstart[d], r1 = rowstart[d + 1];
    float s = brel[0] + q[d];
#pragma unroll 8
    for (uint i = r0; i < r1; i++) s += p[csr_src[i]];
    score[d] = s;
    dkey[d] = ~f2ord(s);  // ascending dkey == descending score
}

// ---------------- radix select (k-th smallest dkey) ----------------
__global__ __launch_bounds__(256) void histK(const uint* __restrict__ dkey, const Scal* __restrict__ sc,
                                             uint* __restrict__ hist, int shift) {
    __shared__ uint lh[256];
    lh[threadIdx.x] = 0u;
    __syncthreads();
    int i = blockIdx.x * 256 + threadIdx.x;
    if (i < Nn) {
        uint d = dkey[i];
        bool ok = (shift == 24) || ((d >> (shift + 8)) == sc->prefix);
        if (ok) atomicAdd(&lh[(d >> shift) & 255u], 1u);
    }
    __syncthreads();
    if (lh[threadIdx.x]) atomicAdd(&hist[threadIdx.x], lh[threadIdx.x]);
}

__global__ void selK(Scal* sc, uint* hist) {
    if (threadIdx.x == 0) {
        uint rem = sc->remaining, cum = 0; int sel = 0;
        for (int b = 0; b < 256; b++) {
            uint c = hist[b];
            if (cum + c >= rem) { sel = b; break; }
            cum += c;
        }
        sc->remaining = rem - cum;
        sc->prefix = (sc->prefix << 8) | (uint)sel;
        for (int b = 0; b < 256; b++) hist[b] = 0u;
    }
}

__global__ __launch_bounds__(256) void cntK(const uint* __restrict__ dkey, const Scal* __restrict__ sc,
                                            uint* __restrict__ blkLt, uint* __restrict__ blkEq) {
    int i = blockIdx.x * 256 + threadIdx.x;
    uint ut = sc->prefix;
    bool lt = (i < Nn) && (dkey[i] < ut);
    bool eq = (i < Nn) && (dkey[i] == ut);
    __shared__ uint sl[4], se[4];
    unsigned long long bl = __ballot(lt), be = __ballot(eq);
    int lane = threadIdx.x & 63, w = threadIdx.x >> 6;
    if (lane == 0) { sl[w] = (uint)__popcll(bl); se[w] = (uint)__popcll(be); }
    __syncthreads();
    if (threadIdx.x == 0) {
        blkLt[blockIdx.x] = sl[0] + sl[1] + sl[2] + sl[3];
        blkEq[blockIdx.x] = se[0] + se[1] + se[2] + se[3];
    }
}

__global__ void prefK(Scal* sc, const uint* blkLt, const uint* blkEq, uint* eqPref) {
    if (threadIdx.x == 0) {
        uint tl = 0, te = 0;
        for (int b = 0; b < NB; b++) {
            eqPref[b] = te;
            tl += blkLt[b];
            te += blkEq[b];
        }
        sc->needEq = Kk - tl;
    }
}

__global__ __launch_bounds__(256) void keptK(const uint* __restrict__ dkey, const Scal* __restrict__ sc,
                                             const uint* __restrict__ eqPref, int* __restrict__ kept) {
    int i = blockIdx.x * 256 + threadIdx.x;
    uint ut = sc->prefix, needEq = sc->needEq;
    bool inr = i < Nn;
    uint d = inr ? dkey[i] : 0xFFFFFFFFu;
    bool isLt = inr && (d < ut);
    bool isEq = inr && (d == ut);
    __shared__ uint wcnt[4];
    unsigned long long mask = __ballot(isEq);
    int lane = threadIdx.x & 63, w = threadIdx.x >> 6;
    uint lanePre = (uint)__popcll(mask & ((1ull << lane) - 1ull));
    if (lane == 0) wcnt[w] = (uint)__popcll(mask);
    __syncthreads();
    uint wo = 0;
    for (int q = 0; q < 4; q++) if (q < w) wo += wcnt[q];
    uint rank = eqPref[blockIdx.x] + wo + lanePre;
    if (inr) kept[i] = (isLt || (isEq && rank < needEq)) ? 1 : 0;
}

// ---------------- layer 2 node transform: bf16 rows, lane owns dims (2l, 2l+1) ----------------
__global__ __launch_bounds__(256) void nodeL2(const float* __restrict__ h1, const float* __restrict__ score,
                                              const int* __restrict__ kept, const float* __restrict__ W2,
                                              const float* __restrict__ as2, const float* __restrict__ ad2,
                                              __hip_bfloat162* __restrict__ h2b, float* __restrict__ alS2,
                                              float* __restrict__ alD2) {
    __shared__ float Ws[16 * 128];
    for (int i = threadIdx.x; i < 2048; i += 256) Ws[i] = W2[i];
    __syncthreads();
    int wid = (blockIdx.x * 256 + threadIdx.x) >> 6;
    int lane = threadIdx.x & 63;
    if (wid >= Nn) return;
    int n = wid;
    if (!kept[n]) return;
    float t = tanhf(score[n]);
    float x2[16];
    const float* hr = h1 + (size_t)n * 16;
#pragma unroll
    for (int j = 0; j < 16; j++) x2[j] = hr[j] * t;
    int d0 = 2 * lane, d1 = 2 * lane + 1;
    float a0 = 0.f, a1 = 0.f;
    const float2* Wv = (const float2*)Ws;
#pragma unroll
    for (int j = 0; j < 16; j++) {
        float2 wv = Wv[j * 64 + lane];
        a0 += x2[j] * wv.x;
        a1 += x2[j] * wv.y;
    }
    __hip_bfloat162 hb;
    hb.x = __float2bfloat16(a0);
    hb.y = __float2bfloat16(a1);
    h2b[(size_t)n * 64 + lane] = hb;
    float s = a0 * as2[d0] + a1 * as2[d1];
    float dd = a0 * ad2[d0] + a1 * ad2[d1];
#pragma unroll
    for (int off = 32; off; off >>= 1) { s += __shfl_xor(s, off); dd += __shfl_xor(dd, off); }
    if (lane == 0) { alS2[n] = s; alD2[n] = dd; }
}

// ---------------- per-slot layer-2 logits (edge-parallel) ----------------
__global__ __launch_bounds__(256) void edgeLg(const int* __restrict__ csr_src, const int* __restrict__ csr_dst,
                                              const float* __restrict__ csr_ea, const int* __restrict__ kept,
                                              const float* __restrict__ alS2, const float* __restrict__ alD2,
                                              const Scal* __restrict__ scc, float* __restrict__ csr_lg) {
    int i = blockIdx.x * 256 + threadIdx.x;
    if (i >= Ee) return;
    int s = csr_src[i];
    int d = csr_dst[i];
    float lg = -1e30f;
    if (kept[s] && kept[d])
        lg = lrelu(alS2[s] + alD2[d] + csr_ea[i] * scc->c2);
    csr_lg[i] = lg;
}

// ---------------- layer-2 m/den per dst: sequential reads only ----------------
__global__ __launch_bounds__(256) void mden2(const float* __restrict__ csr_lg, const uint* __restrict__ rowstart,
                                             float2* __restrict__ md2) {
    int d = blockIdx.x * 256 + threadIdx.x;
    if (d >= Nn) return;
    uint r0 = rowstart[d], r1 = rowstart[d + 1];
    float m = -1e30f;
#pragma unroll 4
    for (uint i = r0; i < r1; i++) m = fmaxf(m, csr_lg[i]);
    float den = 0.f;
#pragma unroll 4
    for (uint i = r0; i < r1; i++) den += __expf(csr_lg[i] - m);  // masked slots underflow to 0
    float rden = (m > -1e29f) ? 1.f / fmaxf(den, 1e-16f) : 0.f;  // all-masked row -> coef 0
    md2[d] = make_float2(m, rden);
}

// ---------------- layer-2 gather: branch-free pure-fma, wave per kept dst ----------------
__global__ __launch_bounds__(256) void gather2b(const int* __restrict__ csr_src,
                                                const float* __restrict__ csr_lg,
                                                const uint* __restrict__ rowstart, const int* __restrict__ kept,
                                                const float2* __restrict__ md2,
                                                const __hip_bfloat162* __restrict__ h2b, const float* __restrict__ b2,
                                                const float* __restrict__ Wg, const float* __restrict__ bg,
                                                float* __restrict__ out2, float* __restrict__ gsc,
                                                Scal* sc) {
    __shared__ float wmax[4];
    int w = threadIdx.x >> 6, lane = threadIdx.x & 63;
    int n = blockIdx.x * 4 + w;
    float lmax = -1e30f;
    if (n < Nn && kept[n]) {
        float2 md = md2[n];
        uint r0 = rowstart[n], r1 = rowstart[n + 1];
        float a0 = 0.f, a1 = 0.f;
#pragma unroll 8
        for (uint i = r0; i < r1; i++) {
            float c = __expf(csr_lg[i] - md.x) * md.y;   // masked: exp underflows to 0
            __hip_bfloat162 hb = h2b[(size_t)csr_src[i] * 64 + lane];
            a0 += c * __bfloat162float(hb.x);
            a1 += c * __bfloat162float(hb.y);
        }
        float2 b2v = ((const float2*)b2)[lane];
        float2 wgv = ((const float2*)Wg)[lane];
        float o0 = fmaxf(a0 + b2v.x, 0.f);
        float o1 = fmaxf(a1 + b2v.y, 0.f);
        ((float2*)(out2 + (size_t)n * 128))[lane] = make_float2(o0, o1);
        float g = o0 * wgv.x + o1 * wgv.y;
#pragma unroll
        for (int off = 32; off; off >>= 1) g += __shfl_xor(g, off);
        g += bg[0];
        if (lane == 0) gsc[n] = g;
        lmax = g;
    }
    if (lane == 0) wmax[w] = lmax;
    __syncthreads();
    if (threadIdx.x == 0) {
        float mm = fmaxf(fmaxf(wmax[0], wmax[1]), fmaxf(wmax[2], wmax[3]));
        atomicMax(&sc->gmaxOrd, f2ord(mm));
    }
}

// gate-weighted sum + per-dim column max; out2 is already post-bias+relu
#define CHUNK 256
__global__ __launch_bounds__(128) void gateB(const float* __restrict__ out2, const float* __restrict__ gsc,
                                             const int* __restrict__ kept, Scal* sc) {
    int d = threadIdx.x;
    float gmax = ord2f(sc->gmaxOrd);
    float acc = 0.f, dacc = 0.f, mx = 0.f;
    int start = blockIdx.x * CHUNK;
    int end = start + CHUNK;
    if (end > Nn) end = Nn;
    for (int n = start; n < end; n++) {
        if (!kept[n]) continue;
        float h = out2[(size_t)n * 128 + d];
        float e = __expf(gsc[n] - gmax);
        acc += e * h;
        mx = fmaxf(mx, h);
        if (d == 0) dacc += e;
    }
    atomicAdd(&sc->attnum[d], acc);
    atomicMax(&sc->mxOrd[d], f2ord(mx));
    if (d == 0) atomicAdd(&sc->deng, dacc);
}

__global__ void outK(const Scal* sc, float* out) {
    int d = threadIdx.x;
    if (d < 128) {
        out[d] = sc->attnum[d] / sc->deng;
        out[128 + d] = ord2f(sc->mxOrd[d]);
    }
}

extern "C" void kernel_launch(void* const* d_in, const int* in_sizes, int n_in,
                              void* d_out, int out_size, void* d_ws, size_t ws_size,
                              hipStream_t stream) {
    const float* x = (const float*)d_in[0];
    const int* ei = (const int*)d_in[1];
    const float* ea = (const float*)d_in[2];
    const float* W1 = (const float*)d_in[3];
    const float* as1 = (const float*)d_in[4];
    const float* ad1 = (const float*)d_in[5];
    const float* We1 = (const float*)d_in[6];
    const float* ae1 = (const float*)d_in[7];
    const float* b1 = (const float*)d_in[8];
    const float* Wrel = (const float*)d_in[9];
    const float* brel = (const float*)d_in[10];
    const float* Wroot = (const float*)d_in[11];
    const float* W2 = (const float*)d_in[12];
    const float* as2 = (const float*)d_in[13];
    const float* ad2 = (const float*)d_in[14];
    const float* We2 = (const float*)d_in[15];
    const float* ae2 = (const float*)d_in[16];
    const float* b2 = (const float*)d_in[17];
    const float* Wg = (const float*)d_in[18];
    const float* bg = (const float*)d_in[19];
    float* out = (float*)d_out;

    float* base = (float*)d_ws;
    // Union region U (12.8M floats): out2 aliases all early-dead buffers.
    float* out2 = base;                               // [12.8M] written by gather2b
    size_t o = 0;
    auto allocU = [&](size_t nf) { float* p2 = base + o; o += nf; return p2; };
    float* hpre = allocU((size_t)Nn * 16);            // dead after gather1b
    float* h1 = allocU((size_t)Nn * 16);              // dead after nodeL2
    float* csr_c1 = allocU((size_t)Ee * 4);           // dead after gather1b
    float* md1f = allocU((size_t)Nn * 8);             // float2[Nn*4], dead after gather1b
    float* alS1 = allocU((size_t)Nn * 4);             // dead after edgeC1
    float* alD1 = allocU((size_t)Nn * 4);             // dead after edgeC1
    float* p = allocU(Nn);                            // dead after scoreK2
    float* q = allocU(Nn);                            // dead after scoreK2
    float* score = allocU(Nn);                        // dead after nodeL2
    uint* dkey = (uint*)allocU(Nn);                   // dead after keptK
    uint* deg = (uint*)allocU(Nn);                    // dead after scanA; reused as cursor
    uint* hist = (uint*)allocU(256);
    uint* blkSum = (uint*)allocU(NB);
    uint* blkOff = (uint*)allocU(NB);
    uint* blkLt = (uint*)allocU(NB);
    uint* blkEq = (uint*)allocU(NB);
    uint* eqPref = (uint*)allocU(NB);
    // o ~= 12.0M < 12.8M — U fits under out2.
    // persistent region after out2
    size_t oo = (size_t)Nn * 128;
    auto alloc = [&](size_t nf) { float* p2 = base + oo; oo += nf; return p2; };
    __hip_bfloat162* h2b = (__hip_bfloat162*)alloc((size_t)Nn * 64);  // bf16 [N][128]
    int* csr_src = (int*)alloc(Ee);
    int* csr_dst = (int*)alloc(Ee);
    float* csr_ea = alloc(Ee);
    float* csr_lg = alloc(Ee);
    float2* md2 = (float2*)alloc((size_t)Nn * 2);
    uint* rowstart = (uint*)alloc(Nn + 1);
    int* kept = (int*)alloc(Nn);
    float* alS2 = alloc(Nn);
    float* alD2 = alloc(Nn);
    float* gsc = alloc(Nn);
    Scal* sc = (Scal*)alloc(512);
    float2* md1 = (float2*)md1f;
    uint* cursor = deg;  // alias: deg dead after scanA, cursor zeroed in scanC

    auto cdiv = [](long a, long b) { return (int)((a + b - 1) / b); };

    initK<<<NB, 256, 0, stream>>>(deg, hist, sc);
    constK<<<1, 64, 0, stream>>>(We1, ae1, We2, ae2, sc);
    nodeL1<<<NB, 256, 0, stream>>>(x, W1, as1, ad1, hpre, alS1, alD1);
    degK<<<cdiv(Ee, 256), 256, 0, stream>>>(ei, deg);
    scanA<<<NB, 256, 0, stream>>>(deg, rowstart, blkSum);
    scanB<<<1, 512, 0, stream>>>(blkSum, blkOff);
    scanC<<<NB, 256, 0, stream>>>(rowstart, blkOff, cursor);
    fillK<<<cdiv(Ee, 256), 256, 0, stream>>>(ei, ea, rowstart, cursor, csr_src, csr_dst, csr_ea);
    edgeC1<<<cdiv(Ee, 256), 256, 0, stream>>>(csr_src, csr_dst, csr_ea, alS1, alD1, sc, csr_c1);
    mden1<<<cdiv((long)Nn * 4, 256), 256, 0, stream>>>(csr_c1, rowstart, md1);
    gather1b<<<cdiv((long)Nn * 4, 256), 256, 0, stream>>>(csr_src, csr_c1, rowstart, md1, hpre,
                                                          b1, Wrel, Wroot, h1, p, q);
    scoreK2<<<NB, 256, 0, stream>>>(csr_src, rowstart, p, q, brel, score, dkey);
    for (int shift = 24; shift >= 0; shift -= 8) {
        histK<<<NB, 256, 0, stream>>>(dkey, sc, hist, shift);
        selK<<<1, 64, 0, stream>>>(sc, hist);
    }
    cntK<<<NB, 256, 0, stream>>>(dkey, sc, blkLt, blkEq);
    prefK<<<1, 64, 0, stream>>>(sc, blkLt, blkEq, eqPref);
    keptK<<<NB, 256, 0, stream>>>(dkey, sc, eqPref, kept);
    nodeL2<<<cdiv(Nn, 4), 256, 0, stream>>>(h1, score, kept, W2, as2, ad2, h2b, alS2, alD2);
    edgeLg<<<cdiv(Ee, 256), 256, 0, stream>>>(csr_src, csr_dst, csr_ea, kept, alS2, alD2, sc, csr_lg);
    mden2<<<NB, 256, 0, stream>>>(csr_lg, rowstart, md2);
    gather2b<<<cdiv(Nn, 4), 256, 0, stream>>>(csr_src, csr_lg, rowstart, kept, md2,
                                              h2b, b2, Wg, bg, out2, gsc, sc);
    gateB<<<cdiv(Nn, CHUNK), 128, 0, stream>>>(out2, gsc, kept, sc);
    outK<<<1, 128, 0, stream>>>(sc, out);
}

// Round 7
// 716.292 us; speedup vs baseline: 1.1046x; 1.0952x over previous
//
#include <hip/hip_runtime.h>
#include <hip/hip_bf16.h>

#define Nn 100000
#define Ee 1600000
#define Kk 80000
#define NB ((Nn + 255) / 256)
#define BIGNEG -1e9f

typedef unsigned int uint;

struct Scal {
    uint prefix, remaining, needEq;
    float c1[4];
    float c2;
    uint gmaxOrd;
    float deng;
    float attnum[128];
    uint mxOrd[128];
};

__device__ __forceinline__ uint f2ord(float f) {
    uint b = __float_as_uint(f);
    return (b & 0x80000000u) ? ~b : (b | 0x80000000u);
}
__device__ __forceinline__ float ord2f(uint u) {
    uint b = (u & 0x80000000u) ? (u ^ 0x80000000u) : ~u;
    return __uint_as_float(b);
}
__device__ __forceinline__ float lrelu(float v) { return v > 0.f ? v : 0.2f * v; }
__device__ __forceinline__ float2 bf2f2(uint u) {
    return make_float2(__uint_as_float(u << 16), __uint_as_float(u & 0xFFFF0000u));
}

// ---------------- init ----------------
__global__ __launch_bounds__(256) void initK(uint* deg, uint* hist, Scal* sc) {
    int i = blockIdx.x * 256 + threadIdx.x;
    if (i < Nn) deg[i] = 0u;
    if (i < 256) hist[i] = 0u;
    if (i < 128) { sc->attnum[i] = 0.f; sc->mxOrd[i] = f2ord(0.0f); }
    if (i == 0) {
        sc->prefix = 0u; sc->remaining = Kk; sc->needEq = 0u;
        sc->deng = 0.f; sc->gmaxOrd = f2ord(-1e30f);
    }
}

__global__ void constK(const float* We1, const float* ae1, const float* We2, const float* ae2,
                       Scal* sc) {
    if (threadIdx.x == 0) {
        for (int h = 0; h < 4; h++) {
            float s = 0.f;
            for (int d = 0; d < 4; d++) s += We1[h * 4 + d] * ae1[h * 4 + d];
            sc->c1[h] = s;
        }
        float s2 = 0.f;
        for (int d = 0; d < 128; d++) s2 += We2[d] * ae2[d];
        sc->c2 = s2;
    }
}

// ---------------- layer 1: node GEMM + attn coefficients ----------------
__global__ __launch_bounds__(256) void nodeL1(const float* __restrict__ x,
                                              const float* __restrict__ W1,
                                              const float* __restrict__ as1,
                                              const float* __restrict__ ad1,
                                              float* __restrict__ hpre,
                                              float* __restrict__ alS1,
                                              float* __restrict__ alD1) {
    __shared__ float Ws[128 * 16];
    __shared__ float s_as[16], s_ad[16];
    for (int i = threadIdx.x; i < 2048; i += 256) Ws[i] = W1[i];
    if (threadIdx.x < 16) { s_as[threadIdx.x] = as1[threadIdx.x]; s_ad[threadIdx.x] = ad1[threadIdx.x]; }
    __syncthreads();
    int n = blockIdx.x * 256 + threadIdx.x;
    if (n >= Nn) return;
    float acc[16];
#pragma unroll
    for (int j = 0; j < 16; j++) acc[j] = 0.f;
    const float4* xr = (const float4*)(x + (size_t)n * 128);
    for (int t4 = 0; t4 < 32; t4++) {
        float4 xv = xr[t4];
#pragma unroll
        for (int j = 0; j < 16; j++) {
            acc[j] += xv.x * Ws[(t4 * 4 + 0) * 16 + j];
            acc[j] += xv.y * Ws[(t4 * 4 + 1) * 16 + j];
            acc[j] += xv.z * Ws[(t4 * 4 + 2) * 16 + j];
            acc[j] += xv.w * Ws[(t4 * 4 + 3) * 16 + j];
        }
    }
    float* hp = hpre + (size_t)n * 16;
#pragma unroll
    for (int j = 0; j < 16; j++) hp[j] = acc[j];
#pragma unroll
    for (int h = 0; h < 4; h++) {
        float s = 0.f, d = 0.f;
#pragma unroll
        for (int q = 0; q < 4; q++) {
            s += acc[h * 4 + q] * s_as[h * 4 + q];
            d += acc[h * 4 + q] * s_ad[h * 4 + q];
        }
        alS1[n * 4 + h] = s;
        alD1[n * 4 + h] = d;
    }
}

// ---------------- CSR build (dst-sorted) ----------------
__global__ __launch_bounds__(256) void degK(const int* __restrict__ ei, uint* __restrict__ deg) {
    int e = blockIdx.x * 256 + threadIdx.x;
    if (e >= Ee) return;
    atomicAdd(&deg[ei[Ee + e]], 1u);
}

__global__ __launch_bounds__(256) void scanA(const uint* __restrict__ deg, uint* __restrict__ rowstart,
                                             uint* __restrict__ blkSum) {
    __shared__ uint s[256];
    int i = blockIdx.x * 256 + threadIdx.x;
    uint v = (i < Nn) ? deg[i] : 0u;
    s[threadIdx.x] = v;
    __syncthreads();
    for (int off = 1; off < 256; off <<= 1) {
        uint t = (threadIdx.x >= off) ? s[threadIdx.x - off] : 0u;
        __syncthreads();
        s[threadIdx.x] += t;
        __syncthreads();
    }
    if (i < Nn) rowstart[i] = s[threadIdx.x] - v;  // exclusive within block
    if (threadIdx.x == 255) blkSum[blockIdx.x] = s[255];
}

__global__ __launch_bounds__(512) void scanB(const uint* __restrict__ blkSum, uint* __restrict__ blkOff) {
    __shared__ uint s[512];
    uint v = (threadIdx.x < NB) ? blkSum[threadIdx.x] : 0u;
    s[threadIdx.x] = v;
    __syncthreads();
    for (int off = 1; off < 512; off <<= 1) {
        uint t = (threadIdx.x >= off) ? s[threadIdx.x - off] : 0u;
        __syncthreads();
        s[threadIdx.x] += t;
        __syncthreads();
    }
    if (threadIdx.x < NB) blkOff[threadIdx.x] = s[threadIdx.x] - v;
}

__global__ __launch_bounds__(256) void scanC(uint* __restrict__ rowstart, const uint* __restrict__ blkOff,
                                             uint* __restrict__ cursor) {
    int i = blockIdx.x * 256 + threadIdx.x;
    if (i < Nn) {
        rowstart[i] += blkOff[blockIdx.x];
        cursor[i] = 0u;
    }
    if (i == 0) rowstart[Nn] = Ee;
}

__global__ __launch_bounds__(256) void fillK(const int* __restrict__ ei, const float* __restrict__ ea,
                                             const uint* __restrict__ rowstart, uint* __restrict__ cursor,
                                             int* __restrict__ csr_src, int* __restrict__ csr_dst,
                                             float* __restrict__ csr_ea) {
    int e = blockIdx.x * 256 + threadIdx.x;
    if (e >= Ee) return;
    int s = ei[e], d = ei[Ee + e];
    uint pos = atomicAdd(&cursor[d], 1u);
    uint idx = rowstart[d] + pos;
    csr_src[idx] = s;
    csr_dst[idx] = d;
    csr_ea[idx] = ea[e];
}

// ---------------- layer-1 per-slot logits (edge-parallel, 4 heads as float4) ----------------
__global__ __launch_bounds__(256) void edgeC1(const int* __restrict__ csr_src, const int* __restrict__ csr_dst,
                                              const float* __restrict__ csr_ea,
                                              const float* __restrict__ alS1, const float* __restrict__ alD1,
                                              const Scal* __restrict__ scc, float* __restrict__ csr_c1) {
    int i = blockIdx.x * 256 + threadIdx.x;
    if (i >= Ee) return;
    int s = csr_src[i], d = csr_dst[i];
    float4 as = *(const float4*)(alS1 + (size_t)s * 4);
    float4 av = *(const float4*)(alD1 + (size_t)d * 4);
    float eav = csr_ea[i];
    float4 o;
    o.x = lrelu(as.x + av.x + eav * scc->c1[0]);
    o.y = lrelu(as.y + av.y + eav * scc->c1[1]);
    o.z = lrelu(as.z + av.z + eav * scc->c1[2]);
    o.w = lrelu(as.w + av.w + eav * scc->c1[3]);
    *(float4*)(csr_c1 + (size_t)i * 4) = o;
}

// ---------------- layer-1 gather: fused max + den/acc, thread per (dst,head) ----------------
__global__ __launch_bounds__(256) void gather1c(const int* __restrict__ csr_src, const float* __restrict__ csr_c1,
                                                const uint* __restrict__ rowstart,
                                                const float* __restrict__ hpre,
                                                const float* __restrict__ b1, const float* __restrict__ Wrel,
                                                const float* __restrict__ Wroot,
                                                float* __restrict__ h1, float* __restrict__ p,
                                                float* __restrict__ q) {
    int tid = blockIdx.x * 256 + threadIdx.x;
    if (tid >= Nn * 4) return;
    int d = tid >> 2, h = tid & 3;
    uint r0 = rowstart[d], r1 = rowstart[d + 1];
    float m = -1e30f;
#pragma unroll 4
    for (uint i = r0; i < r1; i++) m = fmaxf(m, csr_c1[(size_t)i * 4 + h]);
    float den = 0.f;
    float4 acc = {0.f, 0.f, 0.f, 0.f};
#pragma unroll 8
    for (uint i = r0; i < r1; i++) {
        float e = __expf(csr_c1[(size_t)i * 4 + h] - m);
        float4 hv = *(const float4*)(hpre + (size_t)csr_src[i] * 16 + h * 4);
        den += e;
        acc.x += e * hv.x; acc.y += e * hv.y;
        acc.z += e * hv.z; acc.w += e * hv.w;
    }
    float inv = 1.f / fmaxf(den, 1e-16f);
    float4 o;
    o.x = fmaxf(acc.x * inv + b1[h * 4 + 0], 0.f);
    o.y = fmaxf(acc.y * inv + b1[h * 4 + 1], 0.f);
    o.z = fmaxf(acc.z * inv + b1[h * 4 + 2], 0.f);
    o.w = fmaxf(acc.w * inv + b1[h * 4 + 3], 0.f);
    *(float4*)(h1 + (size_t)d * 16 + h * 4) = o;
    // partial dots for GraphConv score: p = h1·Wrel, q = h1·Wroot, reduced over 4 head-lanes
    float pp = o.x * Wrel[h * 4 + 0] + o.y * Wrel[h * 4 + 1] + o.z * Wrel[h * 4 + 2] + o.w * Wrel[h * 4 + 3];
    float qq = o.x * Wroot[h * 4 + 0] + o.y * Wroot[h * 4 + 1] + o.z * Wroot[h * 4 + 2] + o.w * Wroot[h * 4 + 3];
    pp += __shfl_xor(pp, 1); pp += __shfl_xor(pp, 2);
    qq += __shfl_xor(qq, 1); qq += __shfl_xor(qq, 2);
    if (h == 0) { p[d] = pp; q[d] = qq; }
}

// ---------------- SAGPool score: score[d] = brel + q[d] + sum_row p[src] ----------------
__global__ __launch_bounds__(256) void scoreK2(const int* __restrict__ csr_src, const uint* __restrict__ rowstart,
                                               const float* __restrict__ p, const float* __restrict__ q,
                                               const float* __restrict__ brel,
                                               float* __restrict__ score, uint* __restrict__ dkey) {
    int d = blockIdx.x * 256 + threadIdx.x;
    if (d >= Nn) return;
    uint r0 = rowstart[d], r1 = rowstart[d + 1];
    float s = brel[0] + q[d];
#pragma unroll 8
    for (uint i = r0; i < r1; i++) s += p[csr_src[i]];
    score[d] = s;
    dkey[d] = ~f2ord(s);  // ascending dkey == descending score
}

// ---------------- radix select (k-th smallest dkey) ----------------
__global__ __launch_bounds__(256) void histK(const uint* __restrict__ dkey, const Scal* __restrict__ sc,
                                             uint* __restrict__ hist, int shift) {
    __shared__ uint lh[256];
    lh[threadIdx.x] = 0u;
    __syncthreads();
    int i = blockIdx.x * 256 + threadIdx.x;
    if (i < Nn) {
        uint d = dkey[i];
        bool ok = (shift == 24) || ((d >> (shift + 8)) == sc->prefix);
        if (ok) atomicAdd(&lh[(d >> shift) & 255u], 1u);
    }
    __syncthreads();
    if (lh[threadIdx.x]) atomicAdd(&hist[threadIdx.x], lh[threadIdx.x]);
}

// parallel select: 256-thread inclusive scan of hist, exactly one winner updates prefix
__global__ __launch_bounds__(256) void selP(Scal* sc, uint* hist) {
    __shared__ uint s[256];
    int t = threadIdx.x;
    uint c = hist[t];
    s[t] = c;
    __syncthreads();
    for (int off = 1; off < 256; off <<= 1) {
        uint v = (t >= off) ? s[t - off] : 0u;
        __syncthreads();
        s[t] += v;
        __syncthreads();
    }
    uint rem = sc->remaining;
    uint cum = s[t];
    uint cumex = cum - c;
    if (cum >= rem && cumex < rem) {   // first bucket crossing rem (c>0 here)
        sc->remaining = rem - cumex;
        sc->prefix = (sc->prefix << 8) | (uint)t;
    }
    hist[t] = 0u;
}

__global__ __launch_bounds__(256) void cntK(const uint* __restrict__ dkey, const Scal* __restrict__ sc,
                                            uint* __restrict__ blkLt, uint* __restrict__ blkEq) {
    int i = blockIdx.x * 256 + threadIdx.x;
    uint ut = sc->prefix;
    bool lt = (i < Nn) && (dkey[i] < ut);
    bool eq = (i < Nn) && (dkey[i] == ut);
    __shared__ uint sl[4], se[4];
    unsigned long long bl = __ballot(lt), be = __ballot(eq);
    int lane = threadIdx.x & 63, w = threadIdx.x >> 6;
    if (lane == 0) { sl[w] = (uint)__popcll(bl); se[w] = (uint)__popcll(be); }
    __syncthreads();
    if (threadIdx.x == 0) {
        blkLt[blockIdx.x] = sl[0] + sl[1] + sl[2] + sl[3];
        blkEq[blockIdx.x] = se[0] + se[1] + se[2] + se[3];
    }
}

// parallel prefix over the NB block counts (NB=391 <= 512)
__global__ __launch_bounds__(512) void prefP(Scal* sc, const uint* __restrict__ blkLt,
                                             const uint* __restrict__ blkEq, uint* __restrict__ eqPref) {
    __shared__ uint se[512];
    __shared__ uint sl[512];
    int t = threadIdx.x;
    uint e = (t < NB) ? blkEq[t] : 0u;
    uint l = (t < NB) ? blkLt[t] : 0u;
    se[t] = e; sl[t] = l;
    __syncthreads();
    for (int off = 1; off < 512; off <<= 1) {
        uint v1 = (t >= off) ? se[t - off] : 0u;
        uint v2 = (t >= off) ? sl[t - off] : 0u;
        __syncthreads();
        se[t] += v1; sl[t] += v2;
        __syncthreads();
    }
    if (t < NB) eqPref[t] = se[t] - e;
    if (t == 511) sc->needEq = Kk - sl[511];
}

__global__ __launch_bounds__(256) void keptK(const uint* __restrict__ dkey, const Scal* __restrict__ sc,
                                             const uint* __restrict__ eqPref, int* __restrict__ kept) {
    int i = blockIdx.x * 256 + threadIdx.x;
    uint ut = sc->prefix, needEq = sc->needEq;
    bool inr = i < Nn;
    uint d = inr ? dkey[i] : 0xFFFFFFFFu;
    bool isLt = inr && (d < ut);
    bool isEq = inr && (d == ut);
    __shared__ uint wcnt[4];
    unsigned long long mask = __ballot(isEq);
    int lane = threadIdx.x & 63, w = threadIdx.x >> 6;
    uint lanePre = (uint)__popcll(mask & ((1ull << lane) - 1ull));
    if (lane == 0) wcnt[w] = (uint)__popcll(mask);
    __syncthreads();
    uint wo = 0;
    for (int q = 0; q < 4; q++) if (q < w) wo += wcnt[q];
    uint rank = eqPref[blockIdx.x] + wo + lanePre;
    if (inr) kept[i] = (isLt || (isEq && rank < needEq)) ? 1 : 0;
}

// ---------------- layer 2 node transform: bf16 rows, lane owns dims (2l, 2l+1) ----------------
__global__ __launch_bounds__(256) void nodeL2(const float* __restrict__ h1, const float* __restrict__ score,
                                              const int* __restrict__ kept, const float* __restrict__ W2,
                                              const float* __restrict__ as2, const float* __restrict__ ad2,
                                              __hip_bfloat162* __restrict__ h2b, float* __restrict__ alS2,
                                              float* __restrict__ alD2) {
    __shared__ float Ws[16 * 128];
    for (int i = threadIdx.x; i < 2048; i += 256) Ws[i] = W2[i];
    __syncthreads();
    int wid = (blockIdx.x * 256 + threadIdx.x) >> 6;
    int lane = threadIdx.x & 63;
    if (wid >= Nn) return;
    int n = wid;
    if (!kept[n]) return;
    float t = tanhf(score[n]);
    float x2[16];
    const float* hr = h1 + (size_t)n * 16;
#pragma unroll
    for (int j = 0; j < 16; j++) x2[j] = hr[j] * t;
    int d0 = 2 * lane, d1 = 2 * lane + 1;
    float a0 = 0.f, a1 = 0.f;
    const float2* Wv = (const float2*)Ws;
#pragma unroll
    for (int j = 0; j < 16; j++) {
        float2 wv = Wv[j * 64 + lane];
        a0 += x2[j] * wv.x;
        a1 += x2[j] * wv.y;
    }
    __hip_bfloat162 hb;
    hb.x = __float2bfloat16(a0);
    hb.y = __float2bfloat16(a1);
    h2b[(size_t)n * 64 + lane] = hb;
    float s = a0 * as2[d0] + a1 * as2[d1];
    float dd = a0 * ad2[d0] + a1 * ad2[d1];
#pragma unroll
    for (int off = 32; off; off >>= 1) { s += __shfl_xor(s, off); dd += __shfl_xor(dd, off); }
    if (lane == 0) { alS2[n] = s; alD2[n] = dd; }
}

// ---------------- per-slot layer-2 logits (edge-parallel) ----------------
__global__ __launch_bounds__(256) void edgeLg(const int* __restrict__ csr_src, const int* __restrict__ csr_dst,
                                              const float* __restrict__ csr_ea, const int* __restrict__ kept,
                                              const float* __restrict__ alS2, const float* __restrict__ alD2,
                                              const Scal* __restrict__ scc, float* __restrict__ csr_lg) {
    int i = blockIdx.x * 256 + threadIdx.x;
    if (i >= Ee) return;
    int s = csr_src[i];
    int d = csr_dst[i];
    float lg = -1e30f;
    if (kept[s] && kept[d])
        lg = lrelu(alS2[s] + alD2[d] + csr_ea[i] * scc->c2);
    csr_lg[i] = lg;
}

// ---------------- layer-2 gather: wave per dst, 4 edges/iter, 16B lanes, fused max/den ----------------
__global__ __launch_bounds__(256) void gather2c(const int* __restrict__ csr_src,
                                                const float* __restrict__ csr_lg,
                                                const uint* __restrict__ rowstart, const int* __restrict__ kept,
                                                const __hip_bfloat162* __restrict__ h2b, const float* __restrict__ b2,
                                                const float* __restrict__ Wg, const float* __restrict__ bg,
                                                float* __restrict__ out2, float* __restrict__ gsc,
                                                Scal* sc) {
    __shared__ float wmax[4];
    int w = threadIdx.x >> 6, lane = threadIdx.x & 63;
    int g = lane >> 4, t = lane & 15;
    int n = blockIdx.x * 4 + w;
    float lmax = -1e30f;
    if (n < Nn && kept[n]) {
        uint r0 = rowstart[n], r1 = rowstart[n + 1];
        uint len = r1 - r0;
        // lane-parallel row max + butterfly (all lanes end with m)
        float m = -1e30f;
        for (uint i = r0 + lane; i < r1; i += 64) m = fmaxf(m, csr_lg[i]);
#pragma unroll
        for (int off = 32; off; off >>= 1) m = fmaxf(m, __shfl_xor(m, off));
        float scale = (m > -1e29f) ? 1.f : 0.f;   // all-masked row -> zero coefficients
        float den = 0.f;
        float acc[8];
#pragma unroll
        for (int d = 0; d < 8; d++) acc[d] = 0.f;
        const uint* h2u = (const uint*)h2b;
#pragma unroll 2
        for (uint base = 0; base < len; base += 4) {
            uint off = base + (uint)g;
            bool act = off < len;
            uint sidx = act ? (r0 + off) : (r1 - 1);
            float lg = csr_lg[sidx];
            int s = csr_src[sidx];
            float c = act ? __expf(lg - m) * scale : 0.f;   // masked slot: exp underflows to 0
            uint4 hv = *(const uint4*)(h2u + (size_t)s * 64 + t * 4);
            den += c;
            float2 f;
            f = bf2f2(hv.x); acc[0] += c * f.x; acc[1] += c * f.y;
            f = bf2f2(hv.y); acc[2] += c * f.x; acc[3] += c * f.y;
            f = bf2f2(hv.z); acc[4] += c * f.x; acc[5] += c * f.y;
            f = bf2f2(hv.w); acc[6] += c * f.x; acc[7] += c * f.y;
        }
        // reduce across the 4 groups (lanes t, t+16, t+32, t+48)
#pragma unroll
        for (int d = 0; d < 8; d++) {
            acc[d] += __shfl_xor(acc[d], 16);
            acc[d] += __shfl_xor(acc[d], 32);
        }
        den += __shfl_xor(den, 16);
        den += __shfl_xor(den, 32);
        float inv = 1.f / fmaxf(den, 1e-16f);
        float4 b2a = ((const float4*)b2)[t * 2], b2b = ((const float4*)b2)[t * 2 + 1];
        float4 wga = ((const float4*)Wg)[t * 2], wgb = ((const float4*)Wg)[t * 2 + 1];
        float o0 = fmaxf(acc[0] * inv + b2a.x, 0.f);
        float o1 = fmaxf(acc[1] * inv + b2a.y, 0.f);
        float o2 = fmaxf(acc[2] * inv + b2a.z, 0.f);
        float o3 = fmaxf(acc[3] * inv + b2a.w, 0.f);
        float o4 = fmaxf(acc[4] * inv + b2b.x, 0.f);
        float o5 = fmaxf(acc[5] * inv + b2b.y, 0.f);
        float o6 = fmaxf(acc[6] * inv + b2b.z, 0.f);
        float o7 = fmaxf(acc[7] * inv + b2b.w, 0.f);
        if (lane < 16) {
            float4* op = (float4*)(out2 + (size_t)n * 128 + t * 8);
            op[0] = make_float4(o0, o1, o2, o3);
            op[1] = make_float4(o4, o5, o6, o7);
        }
        float gp = o0 * wga.x + o1 * wga.y + o2 * wga.z + o3 * wga.w +
                   o4 * wgb.x + o5 * wgb.y + o6 * wgb.z + o7 * wgb.w;
#pragma unroll
        for (int off = 8; off; off >>= 1) gp += __shfl_xor(gp, off);  // sum over t=0..15
        float gv = gp + bg[0];
        if (lane == 0) gsc[n] = gv;
        lmax = gv;
    }
    if (lane == 0) wmax[w] = lmax;
    __syncthreads();
    if (threadIdx.x == 0) {
        float mm = fmaxf(fmaxf(wmax[0], wmax[1]), fmaxf(wmax[2], wmax[3]));
        atomicMax(&sc->gmaxOrd, f2ord(mm));
    }
}

// gate-weighted sum + per-dim column max; out2 is already post-bias+relu
#define CHUNK 256
__global__ __launch_bounds__(128) void gateB(const float* __restrict__ out2, const float* __restrict__ gsc,
                                             const int* __restrict__ kept, Scal* sc) {
    int d = threadIdx.x;
    float gmax = ord2f(sc->gmaxOrd);
    float acc = 0.f, dacc = 0.f, mx = 0.f;
    int start = blockIdx.x * CHUNK;
    int end = start + CHUNK;
    if (end > Nn) end = Nn;
    for (int n = start; n < end; n++) {
        if (!kept[n]) continue;
        float h = out2[(size_t)n * 128 + d];
        float e = __expf(gsc[n] - gmax);
        acc += e * h;
        mx = fmaxf(mx, h);
        if (d == 0) dacc += e;
    }
    atomicAdd(&sc->attnum[d], acc);
    atomicMax(&sc->mxOrd[d], f2ord(mx));
    if (d == 0) atomicAdd(&sc->deng, dacc);
}

__global__ void outK(const Scal* sc, float* out) {
    int d = threadIdx.x;
    if (d < 128) {
        out[d] = sc->attnum[d] / sc->deng;
        out[128 + d] = ord2f(sc->mxOrd[d]);
    }
}

extern "C" void kernel_launch(void* const* d_in, const int* in_sizes, int n_in,
                              void* d_out, int out_size, void* d_ws, size_t ws_size,
                              hipStream_t stream) {
    const float* x = (const float*)d_in[0];
    const int* ei = (const int*)d_in[1];
    const float* ea = (const float*)d_in[2];
    const float* W1 = (const float*)d_in[3];
    const float* as1 = (const float*)d_in[4];
    const float* ad1 = (const float*)d_in[5];
    const float* We1 = (const float*)d_in[6];
    const float* ae1 = (const float*)d_in[7];
    const float* b1 = (const float*)d_in[8];
    const float* Wrel = (const float*)d_in[9];
    const float* brel = (const float*)d_in[10];
    const float* Wroot = (const float*)d_in[11];
    const float* W2 = (const float*)d_in[12];
    const float* as2 = (const float*)d_in[13];
    const float* ad2 = (const float*)d_in[14];
    const float* We2 = (const float*)d_in[15];
    const float* ae2 = (const float*)d_in[16];
    const float* b2 = (const float*)d_in[17];
    const float* Wg = (const float*)d_in[18];
    const float* bg = (const float*)d_in[19];
    float* out = (float*)d_out;

    float* base = (float*)d_ws;
    // Union region U (12.8M floats): out2 aliases all early-dead buffers.
    float* out2 = base;                               // [12.8M] written by gather2c
    size_t o = 0;
    auto allocU = [&](size_t nf) { float* p2 = base + o; o += nf; return p2; };
    float* hpre = allocU((size_t)Nn * 16);            // dead after gather1c
    float* h1 = allocU((size_t)Nn * 16);              // dead after nodeL2
    float* csr_c1 = allocU((size_t)Ee * 4);           // dead after gather1c
    float* alS1 = allocU((size_t)Nn * 4);             // dead after edgeC1
    float* alD1 = allocU((size_t)Nn * 4);             // dead after edgeC1
    float* p = allocU(Nn);                            // dead after scoreK2
    float* q = allocU(Nn);                            // dead after scoreK2
    float* score = allocU(Nn);                        // dead after nodeL2
    uint* dkey = (uint*)allocU(Nn);                   // dead after keptK
    uint* deg = (uint*)allocU(Nn);                    // dead after scanA; reused as cursor
    uint* hist = (uint*)allocU(256);
    uint* blkSum = (uint*)allocU(NB);
    uint* blkOff = (uint*)allocU(NB);
    uint* blkLt = (uint*)allocU(NB);
    uint* blkEq = (uint*)allocU(NB);
    uint* eqPref = (uint*)allocU(NB);
    // o ~= 11.7M < 12.8M — U fits under out2.
    // persistent region after out2
    size_t oo = (size_t)Nn * 128;
    auto alloc = [&](size_t nf) { float* p2 = base + oo; oo += nf; return p2; };
    __hip_bfloat162* h2b = (__hip_bfloat162*)alloc((size_t)Nn * 64);  // bf16 [N][128]
    int* csr_src = (int*)alloc(Ee);
    int* csr_dst = (int*)alloc(Ee);
    float* csr_ea = alloc(Ee);
    float* csr_lg = alloc(Ee);
    uint* rowstart = (uint*)alloc(Nn + 1);
    int* kept = (int*)alloc(Nn);
    float* alS2 = alloc(Nn);
    float* alD2 = alloc(Nn);
    float* gsc = alloc(Nn);
    Scal* sc = (Scal*)alloc(512);
    uint* cursor = deg;  // alias: deg dead after scanA, cursor zeroed in scanC

    auto cdiv = [](long a, long b) { return (int)((a + b - 1) / b); };

    initK<<<NB, 256, 0, stream>>>(deg, hist, sc);
    constK<<<1, 64, 0, stream>>>(We1, ae1, We2, ae2, sc);
    nodeL1<<<NB, 256, 0, stream>>>(x, W1, as1, ad1, hpre, alS1, alD1);
    degK<<<cdiv(Ee, 256), 256, 0, stream>>>(ei, deg);
    scanA<<<NB, 256, 0, stream>>>(deg, rowstart, blkSum);
    scanB<<<1, 512, 0, stream>>>(blkSum, blkOff);
    scanC<<<NB, 256, 0, stream>>>(rowstart, blkOff, cursor);
    fillK<<<cdiv(Ee, 256), 256, 0, stream>>>(ei, ea, rowstart, cursor, csr_src, csr_dst, csr_ea);
    edgeC1<<<cdiv(Ee, 256), 256, 0, stream>>>(csr_src, csr_dst, csr_ea, alS1, alD1, sc, csr_c1);
    gather1c<<<cdiv((long)Nn * 4, 256), 256, 0, stream>>>(csr_src, csr_c1, rowstart, hpre,
                                                          b1, Wrel, Wroot, h1, p, q);
    scoreK2<<<NB, 256, 0, stream>>>(csr_src, rowstart, p, q, brel, score, dkey);
    for (int shift = 24; shift >= 0; shift -= 8) {
        histK<<<NB, 256, 0, stream>>>(dkey, sc, hist, shift);
        selP<<<1, 256, 0, stream>>>(sc, hist);
    }
    cntK<<<NB, 256, 0, stream>>>(dkey, sc, blkLt, blkEq);
    prefP<<<1, 512, 0, stream>>>(sc, blkLt, blkEq, eqPref);
    keptK<<<NB, 256, 0, stream>>>(dkey, sc, eqPref, kept);
    nodeL2<<<cdiv(Nn, 4), 256, 0, stream>>>(h1, score, kept, W2, as2, ad2, h2b, alS2, alD2);
    edgeLg<<<cdiv(Ee, 256), 256, 0, stream>>>(csr_src, csr_dst, csr_ea, kept, alS2, alD2, sc, csr_lg);
    gather2c<<<cdiv(Nn, 4), 256, 0, stream>>>(csr_src, csr_lg, rowstart, kept,
                                              h2b, b2, Wg, bg, out2, gsc, sc);
    gateB<<<cdiv(Nn, CHUNK), 128, 0, stream>>>(out2, gsc, kept, sc);
    outK<<<1, 128, 0, stream>>>(sc, out);
}

// Round 8
// 471.804 us; speedup vs baseline: 1.6770x; 1.5182x over previous
//
#include <hip/hip_runtime.h>
#include <hip/hip_bf16.h>

#define Nn 100000
#define Ee 1600000
#define Kk 80000
#define NB ((Nn + 255) / 256)
#define BIGNEG -1e9f

typedef unsigned int uint;

struct Scal {
    uint prefix, remaining, needEq;
    float c1[4];
    float c2;
    uint gmaxOrd;
    float deng;
    float attnum[128];
    uint mxOrd[128];
};

__device__ __forceinline__ uint f2ord(float f) {
    uint b = __float_as_uint(f);
    return (b & 0x80000000u) ? ~b : (b | 0x80000000u);
}
__device__ __forceinline__ float ord2f(uint u) {
    uint b = (u & 0x80000000u) ? (u ^ 0x80000000u) : ~u;
    return __uint_as_float(b);
}
__device__ __forceinline__ float lrelu(float v) { return v > 0.f ? v : 0.2f * v; }
__device__ __forceinline__ float2 bf2f2(uint u) {
    return make_float2(__uint_as_float(u << 16), __uint_as_float(u & 0xFFFF0000u));
}

// ---------------- init ----------------
__global__ __launch_bounds__(256) void initK(uint* deg, uint* hist, Scal* sc) {
    int i = blockIdx.x * 256 + threadIdx.x;
    if (i < Nn) deg[i] = 0u;
    if (i < 256) hist[i] = 0u;
    if (i < 128) { sc->attnum[i] = 0.f; sc->mxOrd[i] = f2ord(0.0f); }
    if (i == 0) {
        sc->prefix = 0u; sc->remaining = Kk; sc->needEq = 0u;
        sc->deng = 0.f; sc->gmaxOrd = f2ord(-1e30f);
    }
}

__global__ void constK(const float* We1, const float* ae1, const float* We2, const float* ae2,
                       Scal* sc) {
    if (threadIdx.x == 0) {
        for (int h = 0; h < 4; h++) {
            float s = 0.f;
            for (int d = 0; d < 4; d++) s += We1[h * 4 + d] * ae1[h * 4 + d];
            sc->c1[h] = s;
        }
        float s2 = 0.f;
        for (int d = 0; d < 128; d++) s2 += We2[d] * ae2[d];
        sc->c2 = s2;
    }
}

// ---------------- layer 1: node GEMM + attn coefficients ----------------
__global__ __launch_bounds__(256) void nodeL1(const float* __restrict__ x,
                                              const float* __restrict__ W1,
                                              const float* __restrict__ as1,
                                              const float* __restrict__ ad1,
                                              float* __restrict__ hpre,
                                              float* __restrict__ alS1,
                                              float* __restrict__ alD1) {
    __shared__ float Ws[128 * 16];
    __shared__ float s_as[16], s_ad[16];
    for (int i = threadIdx.x; i < 2048; i += 256) Ws[i] = W1[i];
    if (threadIdx.x < 16) { s_as[threadIdx.x] = as1[threadIdx.x]; s_ad[threadIdx.x] = ad1[threadIdx.x]; }
    __syncthreads();
    int n = blockIdx.x * 256 + threadIdx.x;
    if (n >= Nn) return;
    float acc[16];
#pragma unroll
    for (int j = 0; j < 16; j++) acc[j] = 0.f;
    const float4* xr = (const float4*)(x + (size_t)n * 128);
    for (int t4 = 0; t4 < 32; t4++) {
        float4 xv = xr[t4];
#pragma unroll
        for (int j = 0; j < 16; j++) {
            acc[j] += xv.x * Ws[(t4 * 4 + 0) * 16 + j];
            acc[j] += xv.y * Ws[(t4 * 4 + 1) * 16 + j];
            acc[j] += xv.z * Ws[(t4 * 4 + 2) * 16 + j];
            acc[j] += xv.w * Ws[(t4 * 4 + 3) * 16 + j];
        }
    }
    float* hp = hpre + (size_t)n * 16;
#pragma unroll
    for (int j = 0; j < 16; j++) hp[j] = acc[j];
#pragma unroll
    for (int h = 0; h < 4; h++) {
        float s = 0.f, d = 0.f;
#pragma unroll
        for (int q = 0; q < 4; q++) {
            s += acc[h * 4 + q] * s_as[h * 4 + q];
            d += acc[h * 4 + q] * s_ad[h * 4 + q];
        }
        alS1[n * 4 + h] = s;
        alD1[n * 4 + h] = d;
    }
}

// ---------------- CSR build (dst-sorted) ----------------
__global__ __launch_bounds__(256) void degK(const int* __restrict__ ei, uint* __restrict__ deg) {
    int e = blockIdx.x * 256 + threadIdx.x;
    if (e >= Ee) return;
    atomicAdd(&deg[ei[Ee + e]], 1u);
}

__global__ __launch_bounds__(256) void scanA(const uint* __restrict__ deg, uint* __restrict__ rowstart,
                                             uint* __restrict__ blkSum) {
    __shared__ uint s[256];
    int i = blockIdx.x * 256 + threadIdx.x;
    uint v = (i < Nn) ? deg[i] : 0u;
    s[threadIdx.x] = v;
    __syncthreads();
    for (int off = 1; off < 256; off <<= 1) {
        uint t = (threadIdx.x >= off) ? s[threadIdx.x - off] : 0u;
        __syncthreads();
        s[threadIdx.x] += t;
        __syncthreads();
    }
    if (i < Nn) rowstart[i] = s[threadIdx.x] - v;  // exclusive within block
    if (threadIdx.x == 255) blkSum[blockIdx.x] = s[255];
}

__global__ __launch_bounds__(512) void scanB(const uint* __restrict__ blkSum, uint* __restrict__ blkOff) {
    __shared__ uint s[512];
    uint v = (threadIdx.x < NB) ? blkSum[threadIdx.x] : 0u;
    s[threadIdx.x] = v;
    __syncthreads();
    for (int off = 1; off < 512; off <<= 1) {
        uint t = (threadIdx.x >= off) ? s[threadIdx.x - off] : 0u;
        __syncthreads();
        s[threadIdx.x] += t;
        __syncthreads();
    }
    if (threadIdx.x < NB) blkOff[threadIdx.x] = s[threadIdx.x] - v;
}

__global__ __launch_bounds__(256) void scanC(uint* __restrict__ rowstart, const uint* __restrict__ blkOff,
                                             uint* __restrict__ cursor) {
    int i = blockIdx.x * 256 + threadIdx.x;
    if (i < Nn) {
        rowstart[i] += blkOff[blockIdx.x];
        cursor[i] = 0u;
    }
    if (i == 0) rowstart[Nn] = Ee;
}

__global__ __launch_bounds__(256) void fillK(const int* __restrict__ ei, const float* __restrict__ ea,
                                             const uint* __restrict__ rowstart, uint* __restrict__ cursor,
                                             int* __restrict__ csr_src, int* __restrict__ csr_dst,
                                             float* __restrict__ csr_ea) {
    int e = blockIdx.x * 256 + threadIdx.x;
    if (e >= Ee) return;
    int s = ei[e], d = ei[Ee + e];
    uint pos = atomicAdd(&cursor[d], 1u);
    uint idx = rowstart[d] + pos;
    csr_src[idx] = s;
    csr_dst[idx] = d;
    csr_ea[idx] = ea[e];
}

// ---------------- layer-1 per-slot exp-logits (no max subtraction: logits are O(+-7)) ----------------
__global__ __launch_bounds__(256) void edgeE1(const int* __restrict__ csr_src, const int* __restrict__ csr_dst,
                                              const float* __restrict__ csr_ea,
                                              const float* __restrict__ alS1, const float* __restrict__ alD1,
                                              const Scal* __restrict__ scc, float* __restrict__ csr_e1) {
    int i = blockIdx.x * 256 + threadIdx.x;
    if (i >= Ee) return;
    int s = csr_src[i], d = csr_dst[i];
    float4 as = *(const float4*)(alS1 + (size_t)s * 4);
    float4 av = *(const float4*)(alD1 + (size_t)d * 4);
    float eav = csr_ea[i];
    float4 o;
    o.x = __expf(lrelu(as.x + av.x + eav * scc->c1[0]));
    o.y = __expf(lrelu(as.y + av.y + eav * scc->c1[1]));
    o.z = __expf(lrelu(as.z + av.z + eav * scc->c1[2]));
    o.w = __expf(lrelu(as.w + av.w + eav * scc->c1[3]));
    *(float4*)(csr_e1 + (size_t)i * 4) = o;
}

// ---------------- layer-1 gather: single pass, thread per (dst,head) ----------------
__global__ __launch_bounds__(256) void gather1d(const int* __restrict__ csr_src, const float* __restrict__ csr_e1,
                                                const uint* __restrict__ rowstart,
                                                const float* __restrict__ hpre,
                                                const float* __restrict__ b1, const float* __restrict__ Wrel,
                                                const float* __restrict__ Wroot,
                                                float* __restrict__ h1, float* __restrict__ p,
                                                float* __restrict__ q) {
    int tid = blockIdx.x * 256 + threadIdx.x;
    if (tid >= Nn * 4) return;
    int d = tid >> 2, h = tid & 3;
    uint r0 = rowstart[d], r1 = rowstart[d + 1];
    float den = 0.f;
    float4 acc = {0.f, 0.f, 0.f, 0.f};
#pragma unroll 8
    for (uint i = r0; i < r1; i++) {
        float e = csr_e1[(size_t)i * 4 + h];
        float4 hv = *(const float4*)(hpre + (size_t)csr_src[i] * 16 + h * 4);
        den += e;
        acc.x += e * hv.x; acc.y += e * hv.y;
        acc.z += e * hv.z; acc.w += e * hv.w;
    }
    float inv = 1.f / fmaxf(den, 1e-16f);
    float4 o;
    o.x = fmaxf(acc.x * inv + b1[h * 4 + 0], 0.f);
    o.y = fmaxf(acc.y * inv + b1[h * 4 + 1], 0.f);
    o.z = fmaxf(acc.z * inv + b1[h * 4 + 2], 0.f);
    o.w = fmaxf(acc.w * inv + b1[h * 4 + 3], 0.f);
    *(float4*)(h1 + (size_t)d * 16 + h * 4) = o;
    // partial dots for GraphConv score: p = h1·Wrel, q = h1·Wroot, reduced over 4 head-lanes
    float pp = o.x * Wrel[h * 4 + 0] + o.y * Wrel[h * 4 + 1] + o.z * Wrel[h * 4 + 2] + o.w * Wrel[h * 4 + 3];
    float qq = o.x * Wroot[h * 4 + 0] + o.y * Wroot[h * 4 + 1] + o.z * Wroot[h * 4 + 2] + o.w * Wroot[h * 4 + 3];
    pp += __shfl_xor(pp, 1); pp += __shfl_xor(pp, 2);
    qq += __shfl_xor(qq, 1); qq += __shfl_xor(qq, 2);
    if (h == 0) { p[d] = pp; q[d] = qq; }
}

// ---------------- SAGPool score: score[d] = brel + q[d] + sum_row p[src] ----------------
__global__ __launch_bounds__(256) void scoreK2(const int* __restrict__ csr_src, const uint* __restrict__ rowstart,
                                               const float* __restrict__ p, const float* __restrict__ q,
                                               const float* __restrict__ brel,
                                               float* __restrict__ score, uint* __restrict__ dkey) {
    int d = blockIdx.x * 256 + threadIdx.x;
    if (d >= Nn) return;
    uint r0 = rowstart[d], r1 = rowstart[d + 1];
    float s = brel[0] + q[d];
#pragma unroll 8
    for (uint i = r0; i < r1; i++) s += p[csr_src[i]];
    score[d] = s;
    dkey[d] = ~f2ord(s);  // ascending dkey == descending score
}

// ---------------- radix select (k-th smallest dkey) ----------------
__global__ __launch_bounds__(256) void histK(const uint* __restrict__ dkey, const Scal* __restrict__ sc,
                                             uint* __restrict__ hist, int shift) {
    __shared__ uint lh[256];
    lh[threadIdx.x] = 0u;
    __syncthreads();
    int i = blockIdx.x * 256 + threadIdx.x;
    if (i < Nn) {
        uint d = dkey[i];
        bool ok = (shift == 24) || ((d >> (shift + 8)) == sc->prefix);
        if (ok) atomicAdd(&lh[(d >> shift) & 255u], 1u);
    }
    __syncthreads();
    if (lh[threadIdx.x]) atomicAdd(&hist[threadIdx.x], lh[threadIdx.x]);
}

// parallel select: 256-thread inclusive scan of hist, exactly one winner updates prefix
__global__ __launch_bounds__(256) void selP(Scal* sc, uint* hist) {
    __shared__ uint s[256];
    int t = threadIdx.x;
    uint c = hist[t];
    s[t] = c;
    __syncthreads();
    for (int off = 1; off < 256; off <<= 1) {
        uint v = (t >= off) ? s[t - off] : 0u;
        __syncthreads();
        s[t] += v;
        __syncthreads();
    }
    uint rem = sc->remaining;
    uint cum = s[t];
    uint cumex = cum - c;
    if (cum >= rem && cumex < rem) {   // first bucket crossing rem (c>0 here)
        sc->remaining = rem - cumex;
        sc->prefix = (sc->prefix << 8) | (uint)t;
    }
    hist[t] = 0u;
}

__global__ __launch_bounds__(256) void cntK(const uint* __restrict__ dkey, const Scal* __restrict__ sc,
                                            uint* __restrict__ blkLt, uint* __restrict__ blkEq) {
    int i = blockIdx.x * 256 + threadIdx.x;
    uint ut = sc->prefix;
    bool lt = (i < Nn) && (dkey[i] < ut);
    bool eq = (i < Nn) && (dkey[i] == ut);
    __shared__ uint sl[4], se[4];
    unsigned long long bl = __ballot(lt), be = __ballot(eq);
    int lane = threadIdx.x & 63, w = threadIdx.x >> 6;
    if (lane == 0) { sl[w] = (uint)__popcll(bl); se[w] = (uint)__popcll(be); }
    __syncthreads();
    if (threadIdx.x == 0) {
        blkLt[blockIdx.x] = sl[0] + sl[1] + sl[2] + sl[3];
        blkEq[blockIdx.x] = se[0] + se[1] + se[2] + se[3];
    }
}

// parallel prefix over the NB block counts (NB=391 <= 512)
__global__ __launch_bounds__(512) void prefP(Scal* sc, const uint* __restrict__ blkLt,
                                             const uint* __restrict__ blkEq, uint* __restrict__ eqPref) {
    __shared__ uint se[512];
    __shared__ uint sl[512];
    int t = threadIdx.x;
    uint e = (t < NB) ? blkEq[t] : 0u;
    uint l = (t < NB) ? blkLt[t] : 0u;
    se[t] = e; sl[t] = l;
    __syncthreads();
    for (int off = 1; off < 512; off <<= 1) {
        uint v1 = (t >= off) ? se[t - off] : 0u;
        uint v2 = (t >= off) ? sl[t - off] : 0u;
        __syncthreads();
        se[t] += v1; sl[t] += v2;
        __syncthreads();
    }
    if (t < NB) eqPref[t] = se[t] - e;
    if (t == 511) sc->needEq = Kk - sl[511];
}

__global__ __launch_bounds__(256) void keptK(const uint* __restrict__ dkey, const Scal* __restrict__ sc,
                                             const uint* __restrict__ eqPref, int* __restrict__ kept) {
    int i = blockIdx.x * 256 + threadIdx.x;
    uint ut = sc->prefix, needEq = sc->needEq;
    bool inr = i < Nn;
    uint d = inr ? dkey[i] : 0xFFFFFFFFu;
    bool isLt = inr && (d < ut);
    bool isEq = inr && (d == ut);
    __shared__ uint wcnt[4];
    unsigned long long mask = __ballot(isEq);
    int lane = threadIdx.x & 63, w = threadIdx.x >> 6;
    uint lanePre = (uint)__popcll(mask & ((1ull << lane) - 1ull));
    if (lane == 0) wcnt[w] = (uint)__popcll(mask);
    __syncthreads();
    uint wo = 0;
    for (int q = 0; q < 4; q++) if (q < w) wo += wcnt[q];
    uint rank = eqPref[blockIdx.x] + wo + lanePre;
    if (inr) kept[i] = (isLt || (isEq && rank < needEq)) ? 1 : 0;
}

// ---------------- layer 2 node transform: bf16 rows, lane owns dims (2l, 2l+1) ----------------
__global__ __launch_bounds__(256) void nodeL2(const float* __restrict__ h1, const float* __restrict__ score,
                                              const int* __restrict__ kept, const float* __restrict__ W2,
                                              const float* __restrict__ as2, const float* __restrict__ ad2,
                                              __hip_bfloat162* __restrict__ h2b, float* __restrict__ alS2,
                                              float* __restrict__ alD2) {
    __shared__ float Ws[16 * 128];
    for (int i = threadIdx.x; i < 2048; i += 256) Ws[i] = W2[i];
    __syncthreads();
    int wid = (blockIdx.x * 256 + threadIdx.x) >> 6;
    int lane = threadIdx.x & 63;
    if (wid >= Nn) return;
    int n = wid;
    if (!kept[n]) return;
    float t = tanhf(score[n]);
    float x2[16];
    const float* hr = h1 + (size_t)n * 16;
#pragma unroll
    for (int j = 0; j < 16; j++) x2[j] = hr[j] * t;
    int d0 = 2 * lane, d1 = 2 * lane + 1;
    float a0 = 0.f, a1 = 0.f;
    const float2* Wv = (const float2*)Ws;
#pragma unroll
    for (int j = 0; j < 16; j++) {
        float2 wv = Wv[j * 64 + lane];
        a0 += x2[j] * wv.x;
        a1 += x2[j] * wv.y;
    }
    __hip_bfloat162 hb;
    hb.x = __float2bfloat16(a0);
    hb.y = __float2bfloat16(a1);
    h2b[(size_t)n * 64 + lane] = hb;
    float s = a0 * as2[d0] + a1 * as2[d1];
    float dd = a0 * ad2[d0] + a1 * ad2[d1];
#pragma unroll
    for (int off = 32; off; off >>= 1) { s += __shfl_xor(s, off); dd += __shfl_xor(dd, off); }
    if (lane == 0) { alS2[n] = s; alD2[n] = dd; }
}

// ---------------- per-slot layer-2 exp-logits (edge-parallel, masked -> 0) ----------------
__global__ __launch_bounds__(256) void edgeCe(const int* __restrict__ csr_src, const int* __restrict__ csr_dst,
                                              const float* __restrict__ csr_ea, const int* __restrict__ kept,
                                              const float* __restrict__ alS2, const float* __restrict__ alD2,
                                              const Scal* __restrict__ scc, float* __restrict__ csr_ce) {
    int i = blockIdx.x * 256 + threadIdx.x;
    if (i >= Ee) return;
    int s = csr_src[i];
    int d = csr_dst[i];
    float ce = 0.f;
    if (kept[s] && kept[d])
        ce = __expf(lrelu(alS2[s] + alD2[d] + csr_ea[i] * scc->c2));
    csr_ce[i] = ce;
}

// ---------------- layer-2 gather: grid-stride wave per node, 4 edges/iter, single pass ----------------
__global__ __launch_bounds__(256) void gather2d(const int* __restrict__ csr_src,
                                                const float* __restrict__ csr_ce,
                                                const uint* __restrict__ rowstart, const int* __restrict__ kept,
                                                const __hip_bfloat162* __restrict__ h2b, const float* __restrict__ b2,
                                                const float* __restrict__ Wg, const float* __restrict__ bg,
                                                float* __restrict__ out2, float* __restrict__ gsc) {
    int w = threadIdx.x >> 6, lane = threadIdx.x & 63;
    int g = lane >> 4, t = lane & 15;
    float4 b2a = ((const float4*)b2)[t * 2], b2b = ((const float4*)b2)[t * 2 + 1];
    float4 wga = ((const float4*)Wg)[t * 2], wgb = ((const float4*)Wg)[t * 2 + 1];
    float bg0 = bg[0];
    const uint* h2u = (const uint*)h2b;
    for (int n = blockIdx.x * 4 + w; n < Nn; n += gridDim.x * 4) {
        if (!kept[n]) continue;
        uint r0 = rowstart[n];
        uint len = rowstart[n + 1] - r0;
        float den = 0.f;
        float acc[8];
#pragma unroll
        for (int d = 0; d < 8; d++) acc[d] = 0.f;
#pragma unroll 2
        for (uint base = 0; base < len; base += 4) {
            uint off = base + (uint)g;
            bool act = off < len;
            uint sidx = act ? (r0 + off) : (r0 + len - 1);
            float c = act ? csr_ce[sidx] : 0.f;      // masked slots already 0
            int s = csr_src[sidx];
            uint4 hv = *(const uint4*)(h2u + (size_t)s * 64 + t * 4);
            den += c;
            float2 f;
            f = bf2f2(hv.x); acc[0] += c * f.x; acc[1] += c * f.y;
            f = bf2f2(hv.y); acc[2] += c * f.x; acc[3] += c * f.y;
            f = bf2f2(hv.z); acc[4] += c * f.x; acc[5] += c * f.y;
            f = bf2f2(hv.w); acc[6] += c * f.x; acc[7] += c * f.y;
        }
        // reduce across the 4 groups (lanes t, t+16, t+32, t+48)
#pragma unroll
        for (int d = 0; d < 8; d++) {
            acc[d] += __shfl_xor(acc[d], 16);
            acc[d] += __shfl_xor(acc[d], 32);
        }
        den += __shfl_xor(den, 16);
        den += __shfl_xor(den, 32);
        float inv = 1.f / fmaxf(den, 1e-16f);
        float o0 = fmaxf(acc[0] * inv + b2a.x, 0.f);
        float o1 = fmaxf(acc[1] * inv + b2a.y, 0.f);
        float o2 = fmaxf(acc[2] * inv + b2a.z, 0.f);
        float o3 = fmaxf(acc[3] * inv + b2a.w, 0.f);
        float o4 = fmaxf(acc[4] * inv + b2b.x, 0.f);
        float o5 = fmaxf(acc[5] * inv + b2b.y, 0.f);
        float o6 = fmaxf(acc[6] * inv + b2b.z, 0.f);
        float o7 = fmaxf(acc[7] * inv + b2b.w, 0.f);
        if (lane < 16) {
            float4* op = (float4*)(out2 + (size_t)n * 128 + t * 8);
            op[0] = make_float4(o0, o1, o2, o3);
            op[1] = make_float4(o4, o5, o6, o7);
        }
        float gp = o0 * wga.x + o1 * wga.y + o2 * wga.z + o3 * wga.w +
                   o4 * wgb.x + o5 * wgb.y + o6 * wgb.z + o7 * wgb.w;
#pragma unroll
        for (int off = 8; off; off >>= 1) gp += __shfl_xor(gp, off);  // sum over t=0..15
        if (lane == 0) gsc[n] = gp + bg0;
    }
}

// gate-weighted sum + per-dim column max; out2 is already post-bias+relu; exp without max (gsc ~ O(1))
#define CHUNK 256
__global__ __launch_bounds__(128) void gateB(const float* __restrict__ out2, const float* __restrict__ gsc,
                                             const int* __restrict__ kept, Scal* sc) {
    int d = threadIdx.x;
    float acc = 0.f, dacc = 0.f, mx = 0.f;
    int start = blockIdx.x * CHUNK;
    int end = start + CHUNK;
    if (end > Nn) end = Nn;
    for (int n = start; n < end; n++) {
        if (!kept[n]) continue;
        float h = out2[(size_t)n * 128 + d];
        float e = __expf(gsc[n]);
        acc += e * h;
        mx = fmaxf(mx, h);
        if (d == 0) dacc += e;
    }
    atomicAdd(&sc->attnum[d], acc);
    atomicMax(&sc->mxOrd[d], f2ord(mx));
    if (d == 0) atomicAdd(&sc->deng, dacc);
}

__global__ void outK(const Scal* sc, float* out) {
    int d = threadIdx.x;
    if (d < 128) {
        out[d] = sc->attnum[d] / sc->deng;
        out[128 + d] = ord2f(sc->mxOrd[d]);
    }
}

extern "C" void kernel_launch(void* const* d_in, const int* in_sizes, int n_in,
                              void* d_out, int out_size, void* d_ws, size_t ws_size,
                              hipStream_t stream) {
    const float* x = (const float*)d_in[0];
    const int* ei = (const int*)d_in[1];
    const float* ea = (const float*)d_in[2];
    const float* W1 = (const float*)d_in[3];
    const float* as1 = (const float*)d_in[4];
    const float* ad1 = (const float*)d_in[5];
    const float* We1 = (const float*)d_in[6];
    const float* ae1 = (const float*)d_in[7];
    const float* b1 = (const float*)d_in[8];
    const float* Wrel = (const float*)d_in[9];
    const float* brel = (const float*)d_in[10];
    const float* Wroot = (const float*)d_in[11];
    const float* W2 = (const float*)d_in[12];
    const float* as2 = (const float*)d_in[13];
    const float* ad2 = (const float*)d_in[14];
    const float* We2 = (const float*)d_in[15];
    const float* ae2 = (const float*)d_in[16];
    const float* b2 = (const float*)d_in[17];
    const float* Wg = (const float*)d_in[18];
    const float* bg = (const float*)d_in[19];
    float* out = (float*)d_out;

    float* base = (float*)d_ws;
    // Union region U (12.8M floats): out2 aliases all early-dead buffers.
    float* out2 = base;                               // [12.8M] written by gather2d
    size_t o = 0;
    auto allocU = [&](size_t nf) { float* p2 = base + o; o += nf; return p2; };
    float* hpre = allocU((size_t)Nn * 16);            // dead after gather1d
    float* h1 = allocU((size_t)Nn * 16);              // dead after nodeL2
    float* csr_e1 = allocU((size_t)Ee * 4);           // dead after gather1d
    float* alS1 = allocU((size_t)Nn * 4);             // dead after edgeE1
    float* alD1 = allocU((size_t)Nn * 4);             // dead after edgeE1
    float* p = allocU(Nn);                            // dead after scoreK2
    float* q = allocU(Nn);                            // dead after scoreK2
    float* score = allocU(Nn);                        // dead after nodeL2
    uint* dkey = (uint*)allocU(Nn);                   // dead after keptK
    uint* deg = (uint*)allocU(Nn);                    // dead after scanA; reused as cursor
    uint* hist = (uint*)allocU(256);
    uint* blkSum = (uint*)allocU(NB);
    uint* blkOff = (uint*)allocU(NB);
    uint* blkLt = (uint*)allocU(NB);
    uint* blkEq = (uint*)allocU(NB);
    uint* eqPref = (uint*)allocU(NB);
    // o ~= 11.7M < 12.8M — U fits under out2.
    // persistent region after out2
    size_t oo = (size_t)Nn * 128;
    auto alloc = [&](size_t nf) { float* p2 = base + oo; oo += nf; return p2; };
    __hip_bfloat162* h2b = (__hip_bfloat162*)alloc((size_t)Nn * 64);  // bf16 [N][128]
    int* csr_src = (int*)alloc(Ee);
    int* csr_dst = (int*)alloc(Ee);
    float* csr_ea = alloc(Ee);
    float* csr_ce = alloc(Ee);
    uint* rowstart = (uint*)alloc(Nn + 1);
    int* kept = (int*)alloc(Nn);
    float* alS2 = alloc(Nn);
    float* alD2 = alloc(Nn);
    float* gsc = alloc(Nn);
    Scal* sc = (Scal*)alloc(512);
    uint* cursor = deg;  // alias: deg dead after scanA, cursor zeroed in scanC

    auto cdiv = [](long a, long b) { return (int)((a + b - 1) / b); };

    initK<<<NB, 256, 0, stream>>>(deg, hist, sc);
    constK<<<1, 64, 0, stream>>>(We1, ae1, We2, ae2, sc);
    nodeL1<<<NB, 256, 0, stream>>>(x, W1, as1, ad1, hpre, alS1, alD1);
    degK<<<cdiv(Ee, 256), 256, 0, stream>>>(ei, deg);
    scanA<<<NB, 256, 0, stream>>>(deg, rowstart, blkSum);
    scanB<<<1, 512, 0, stream>>>(blkSum, blkOff);
    scanC<<<NB, 256, 0, stream>>>(rowstart, blkOff, cursor);
    fillK<<<cdiv(Ee, 256), 256, 0, stream>>>(ei, ea, rowstart, cursor, csr_src, csr_dst, csr_ea);
    edgeE1<<<cdiv(Ee, 256), 256, 0, stream>>>(csr_src, csr_dst, csr_ea, alS1, alD1, sc, csr_e1);
    gather1d<<<cdiv((long)Nn * 4, 256), 256, 0, stream>>>(csr_src, csr_e1, rowstart, hpre,
                                                          b1, Wrel, Wroot, h1, p, q);
    scoreK2<<<NB, 256, 0, stream>>>(csr_src, rowstart, p, q, brel, score, dkey);
    for (int shift = 24; shift >= 0; shift -= 8) {
        histK<<<NB, 256, 0, stream>>>(dkey, sc, hist, shift);
        selP<<<1, 256, 0, stream>>>(sc, hist);
    }
    cntK<<<NB, 256, 0, stream>>>(dkey, sc, blkLt, blkEq);
    prefP<<<1, 512, 0, stream>>>(sc, blkLt, blkEq, eqPref);
    keptK<<<NB, 256, 0, stream>>>(dkey, sc, eqPref, kept);
    nodeL2<<<cdiv(Nn, 4), 256, 0, stream>>>(h1, score, kept, W2, as2, ad2, h2b, alS2, alD2);
    edgeCe<<<cdiv(Ee, 256), 256, 0, stream>>>(csr_src, csr_dst, csr_ea, kept, alS2, alD2, sc, csr_ce);
    gather2d<<<2048, 256, 0, stream>>>(csr_src, csr_ce, rowstart, kept,
                                       h2b, b2, Wg, bg, out2, gsc);
    gateB<<<cdiv(Nn, CHUNK), 128, 0, stream>>>(out2, gsc, kept, sc);
    outK<<<1, 128, 0, stream>>>(sc, out);
}